// Round 1
// baseline (1253.329 us; speedup 1.0000x reference)
//
#include <hip/hip_runtime.h>
#include <hip/hip_bf16.h>

typedef __attribute__((ext_vector_type(8))) short   s16x8;
typedef __attribute__((ext_vector_type(8))) __bf16  bf16x8;
typedef __attribute__((ext_vector_type(4))) float   f32x4;

#define DEV static __device__ __forceinline__

DEV short f2bf(float f) {
  unsigned u = __builtin_bit_cast(unsigned, f);
  u = (u + 0x7fff + ((u >> 16) & 1)) >> 16;
  return (short)u;
}
DEV float bf2f(short s) {
  unsigned u = ((unsigned)(unsigned short)s) << 16;
  return __builtin_bit_cast(float, u);
}

// ---------------- cast fp32 -> bf16, 8 elems/thread ----------------
__global__ __launch_bounds__(256) void cast8_kernel(const float* __restrict__ in,
                                                    short* __restrict__ out, long n) {
  long i = ((long)blockIdx.x * 256 + threadIdx.x) * 8;
  if (i >= n) return;
  float4 a = *(const float4*)(in + i);
  float4 b = *(const float4*)(in + i + 4);
  s16x8 o;
  o[0] = f2bf(a.x); o[1] = f2bf(a.y); o[2] = f2bf(a.z); o[3] = f2bf(a.w);
  o[4] = f2bf(b.x); o[5] = f2bf(b.y); o[6] = f2bf(b.z); o[7] = f2bf(b.w);
  *(s16x8*)(out + i) = o;
}

// ---------------- GEMM: C[M][N] = A[M][K] @ W[N][K]^T (bf16 in, fp32 acc) ---
// 128x128 tile, 4 waves (2x2), BK=32, each wave 64x64 = 4x4 frags of 16x16.
// MODE 0: plain fp32 C write (N=4096).  MODE 1: qkv split epilogue (N=6144).
template<int MODE>
__global__ __launch_bounds__(256) void gemm_bt(
    const short* __restrict__ A, const short* __restrict__ W,
    float* __restrict__ Cout,
    short* __restrict__ qb, short* __restrict__ kb, short* __restrict__ vb,
    float* __restrict__ nk, float* __restrict__ nv)
{
  const int K = 4096;
  __shared__ short As[128 * 32];
  __shared__ short Ws[128 * 32];
  const int tid = threadIdx.x;
  const int lane = tid & 63;
  const int w = tid >> 6;
  const int wm = w >> 1, wn = w & 1;
  const int tm = blockIdx.y, tn = blockIdx.x;
  const int l15 = lane & 15, koff = (lane >> 4) * 8;

  f32x4 zero = {0.f, 0.f, 0.f, 0.f};
  f32x4 acc[4][4];
  #pragma unroll
  for (int i = 0; i < 4; ++i)
    #pragma unroll
    for (int j = 0; j < 4; ++j) acc[i][j] = zero;

  const int e0 = tid * 8, e1 = tid * 8 + 2048;
  const int r0 = e0 >> 5, c0 = e0 & 31;
  const int r1 = e1 >> 5, c1 = e1 & 31;
  const long arow0 = (long)(tm * 128 + r0) * K;
  const long arow1 = (long)(tm * 128 + r1) * K;
  const long wrow0 = (long)(tn * 128 + r0) * K;
  const long wrow1 = (long)(tn * 128 + r1) * K;

  for (int k0 = 0; k0 < K; k0 += 32) {
    __syncthreads();
    s16x8 ta0 = *(const s16x8*)&A[arow0 + k0 + c0];
    s16x8 ta1 = *(const s16x8*)&A[arow1 + k0 + c1];
    s16x8 tw0 = *(const s16x8*)&W[wrow0 + k0 + c0];
    s16x8 tw1 = *(const s16x8*)&W[wrow1 + k0 + c1];
    *(s16x8*)&As[e0] = ta0;
    *(s16x8*)&As[e1] = ta1;
    *(s16x8*)&Ws[e0] = tw0;
    *(s16x8*)&Ws[e1] = tw1;
    __syncthreads();
    bf16x8 af[4], wf[4];
    #pragma unroll
    for (int i = 0; i < 4; ++i) {
      af[i] = *(const bf16x8*)&As[(wm * 64 + i * 16 + l15) * 32 + koff];
      wf[i] = *(const bf16x8*)&Ws[(wn * 64 + i * 16 + l15) * 32 + koff];
    }
    #pragma unroll
    for (int i = 0; i < 4; ++i)
      #pragma unroll
      for (int j = 0; j < 4; ++j)
        acc[i][j] = __builtin_amdgcn_mfma_f32_16x16x32_bf16(af[i], wf[j], acc[i][j], 0, 0, 0);
  }

  #pragma unroll
  for (int i = 0; i < 4; ++i) {
    int mbase = tm * 128 + wm * 64 + i * 16 + (lane >> 4) * 4;
    #pragma unroll
    for (int j = 0; j < 4; ++j) {
      int col = tn * 128 + wn * 64 + j * 16 + l15;
      #pragma unroll
      for (int r = 0; r < 4; ++r) {
        int m = mbase + r;
        float v = acc[i][j][r];
        if (MODE == 0) {
          Cout[(long)m * 4096 + col] = v;
        } else {
          int b = m >> 11, s = m & 2047;
          if (col < 4096) {
            int h = col >> 7, d = col & 127;
            qb[((long)((b * 32 + h) * 2048 + s)) * 128 + d] = f2bf(v);
          } else if (col < 5120) {
            int c2 = col - 4096;
            int h = c2 >> 7, d = c2 & 127;
            long o = ((long)((b * 8 + h) * 2048 + s)) * 128 + d;
            kb[o] = f2bf(v);
            nk[o] = v;
          } else {
            int c2 = col - 5120;
            int h = c2 >> 7, d = c2 & 127;
            long o = ((long)((b * 8 + h) * 2048 + s)) * 128 + d;
            vb[o] = f2bf(v);
            nv[o] = v;
          }
        }
      }
    }
  }
}

// ---------------- RoPE in-place on q and k (bf16, interleaved pairs) --------
__global__ __launch_bounds__(256) void rope_kernel(short* __restrict__ qb,
                                                   short* __restrict__ kb) {
  const long QV = 2097152;  // q vectors of 8 elems: 2*32*2048*128/8
  const long TV = 2621440;  // + k vectors: 2*8*2048*128/8
  long i = (long)blockIdx.x * 256 + threadIdx.x;
  if (i >= TV) return;
  short* p;
  long e;
  if (i < QV) { e = i * 8; p = qb + e; }
  else        { e = (i - QV) * 8; p = kb + e; }
  int d0 = (int)(e & 127);
  int s  = (int)((e >> 7) & 2047);
  int jb = d0 >> 1;
  s16x8 v = *(const s16x8*)p;
  #pragma unroll
  for (int t = 0; t < 4; ++t) {
    float x1 = bf2f(v[2 * t]), x2 = bf2f(v[2 * t + 1]);
    int j = jb + t;
    float inv = __expf(-0.14391157f * (float)j);  // 10000^(-2j/128)
    float ang = (float)s * inv;
    float sn, cs;
    __sincosf(ang, &sn, &cs);
    v[2 * t]     = f2bf(x1 * cs - x2 * sn);
    v[2 * t + 1] = f2bf(x1 * sn + x2 * cs);
  }
  *(s16x8*)p = v;
}

// ---------------- Flash attention, causal, GQA 4:1 --------------------------
// grid (S/64, H, B), 256 thr = 4 waves, wave = 16 q rows, KV tile = 32.
__global__ __launch_bounds__(256) void flash_kernel(
    const short* __restrict__ qb, const short* __restrict__ kb,
    const short* __restrict__ vb, short* __restrict__ ao)
{
  const int qt = blockIdx.x, h = blockIdx.y, b = blockIdx.z;
  const int hkv = h >> 2;
  const int tid = threadIdx.x, w = tid >> 6, lane = tid & 63;
  const int l15 = lane & 15, koff = (lane >> 4) * 8;
  const int qbase = qt * 64, q0 = qbase + w * 16;

  const short* Q  = qb + (long)(b * 32 + h) * 2048 * 128;
  const short* Kp = kb + (long)(b * 8 + hkv) * 2048 * 128;
  const short* Vp = vb + (long)(b * 8 + hkv) * 2048 * 128;

  __shared__ short Vt[128 * 32];  // V^T tile: [d][kk]
  __shared__ short Pl[4][512];    // per-wave P: [16 q][32 kv]

  bf16x8 qf[4];
  #pragma unroll
  for (int ks = 0; ks < 4; ++ks)
    qf[ks] = *(const bf16x8*)&Q[(long)(q0 + l15) * 128 + ks * 32 + koff];

  f32x4 zero = {0.f, 0.f, 0.f, 0.f};
  f32x4 o[8];
  #pragma unroll
  for (int db = 0; db < 8; ++db) o[db] = zero;
  float m_[4], l_[4];
  #pragma unroll
  for (int r = 0; r < 4; ++r) { m_[r] = -1e30f; l_[r] = 0.f; }

  const int nt = (qbase + 64) >> 5;
  for (int t = 0; t < nt; ++t) {
    const int kv0 = t * 32;
    __syncthreads();
    {  // stage V^T cooperatively: thread -> (kv row, 16-wide d segment)
      const int kk = tid >> 3;
      const int d0 = (tid & 7) * 16;
      const short* src = &Vp[(long)(kv0 + kk) * 128 + d0];
      s16x8 v0 = *(const s16x8*)src;
      s16x8 v1 = *(const s16x8*)(src + 8);
      #pragma unroll
      for (int jj = 0; jj < 8; ++jj) Vt[(d0 + jj) * 32 + kk] = v0[jj];
      #pragma unroll
      for (int jj = 0; jj < 8; ++jj) Vt[(d0 + 8 + jj) * 32 + kk] = v1[jj];
    }
    __syncthreads();

    // S = Q K^T (16 q x 32 kv), two 16-col halves
    f32x4 sc[2];
    sc[0] = zero; sc[1] = zero;
    #pragma unroll
    for (int ks = 0; ks < 4; ++ks) {
      bf16x8 kf0 = *(const bf16x8*)&Kp[(long)(kv0 + l15) * 128 + ks * 32 + koff];
      bf16x8 kf1 = *(const bf16x8*)&Kp[(long)(kv0 + 16 + l15) * 128 + ks * 32 + koff];
      sc[0] = __builtin_amdgcn_mfma_f32_16x16x32_bf16(qf[ks], kf0, sc[0], 0, 0, 0);
      sc[1] = __builtin_amdgcn_mfma_f32_16x16x32_bf16(qf[ks], kf1, sc[1], 0, 0, 0);
    }

    const float scale = 0.08838834764831845f;  // 1/sqrt(128)
    float pv0[4], pv1[4];
    #pragma unroll
    for (int r = 0; r < 4; ++r) {
      int q_abs = q0 + (lane >> 4) * 4 + r;
      int kva = kv0 + l15, kvb = kv0 + 16 + l15;
      float s0 = sc[0][r] * scale, s1 = sc[1][r] * scale;
      if (kva > q_abs) s0 = -1e30f;
      if (kvb > q_abs) s1 = -1e30f;
      pv0[r] = s0; pv1[r] = s1;
    }
    #pragma unroll
    for (int r = 0; r < 4; ++r) {
      float mx = fmaxf(pv0[r], pv1[r]);
      mx = fmaxf(mx, __shfl_xor(mx, 1));
      mx = fmaxf(mx, __shfl_xor(mx, 2));
      mx = fmaxf(mx, __shfl_xor(mx, 4));
      mx = fmaxf(mx, __shfl_xor(mx, 8));
      float mn = fmaxf(m_[r], mx);
      float fac = __expf(m_[r] - mn);
      float p0 = __expf(pv0[r] - mn);
      float p1 = __expf(pv1[r] - mn);
      pv0[r] = p0; pv1[r] = p1;
      float rs = p0 + p1;
      rs += __shfl_xor(rs, 1);
      rs += __shfl_xor(rs, 2);
      rs += __shfl_xor(rs, 4);
      rs += __shfl_xor(rs, 8);
      l_[r] = l_[r] * fac + rs;
      m_[r] = mn;
      #pragma unroll
      for (int db = 0; db < 8; ++db) o[db][r] *= fac;
    }
    // P (C-layout) -> LDS -> A-layout fragment
    #pragma unroll
    for (int r = 0; r < 4; ++r) {
      int row = (lane >> 4) * 4 + r;
      Pl[w][row * 32 + l15]      = f2bf(pv0[r]);
      Pl[w][row * 32 + 16 + l15] = f2bf(pv1[r]);
    }
    asm volatile("s_waitcnt lgkmcnt(0)" ::: "memory");
    __builtin_amdgcn_sched_barrier(0);
    bf16x8 pa = *(const bf16x8*)&Pl[w][l15 * 32 + koff];
    #pragma unroll
    for (int db = 0; db < 8; ++db) {
      bf16x8 vf = *(const bf16x8*)&Vt[(db * 16 + l15) * 32 + koff];
      o[db] = __builtin_amdgcn_mfma_f32_16x16x32_bf16(pa, vf, o[db], 0, 0, 0);
    }
  }

  #pragma unroll
  for (int db = 0; db < 8; ++db) {
    int d = db * 16 + l15;
    #pragma unroll
    for (int r = 0; r < 4; ++r) {
      int qrow = (lane >> 4) * 4 + r;
      float val = o[db][r] / l_[r];
      ao[((long)(b * 2048 + q0 + qrow)) * 4096 + h * 128 + d] = f2bf(val);
    }
  }
}

// ---------------- launcher --------------------------------------------------
extern "C" void kernel_launch(void* const* d_in, const int* in_sizes, int n_in,
                              void* d_out, int out_size, void* d_ws, size_t ws_size,
                              hipStream_t stream) {
  const float* x  = (const float*)d_in[0];
  const float* wq = (const float*)d_in[1];
  const float* wk = (const float*)d_in[2];
  const float* wv = (const float*)d_in[3];
  const float* wo = (const float*)d_in[4];
  float* out = (float*)d_out;

  char* ws = (char*)d_ws;
  short* xb    = (short*)(ws);               // 33554432 B  (x bf16; later reused as attn_out)
  short* wqkvb = (short*)(ws + 33554432);    // 50331648 B  (wq|wk|wv bf16, 6144x4096)
  short* wob   = (short*)(ws + 83886080);    // 33554432 B
  short* qb    = (short*)(ws + 117440512);   // 33554432 B  (B,H,S,D)
  short* kb    = (short*)(ws + 150994944);   // 8388608 B   (B,Hkv,S,D)
  short* vb    = (short*)(ws + 159383552);   // 8388608 B
  short* ao    = xb;                         // attn output bf16 (B,S,H*D), reuses xb

  float* nk = out + 16777216;  // new_k fp32 (B,Hkv,S,D)
  float* nv = out + 20971520;  // new_v fp32

  cast8_kernel<<<8192, 256, 0, stream>>>(x,  xb,    16777216);
  cast8_kernel<<<8192, 256, 0, stream>>>(wq, wqkvb, 16777216);
  cast8_kernel<<<2048, 256, 0, stream>>>(wk, wqkvb + 16777216, 4194304);
  cast8_kernel<<<2048, 256, 0, stream>>>(wv, wqkvb + 20971520, 4194304);
  cast8_kernel<<<8192, 256, 0, stream>>>(wo, wob,   16777216);

  gemm_bt<1><<<dim3(48, 32), 256, 0, stream>>>(xb, wqkvb, nullptr, qb, kb, vb, nk, nv);
  rope_kernel<<<10240, 256, 0, stream>>>(qb, kb);
  flash_kernel<<<dim3(32, 32, 2), 256, 0, stream>>>(qb, kb, vb, ao);
  gemm_bt<0><<<dim3(32, 32), 256, 0, stream>>>(ao, wob, out, nullptr, nullptr, nullptr,
                                               nullptr, nullptr);
}

// Round 2
// 1058.972 us; speedup vs baseline: 1.1835x; 1.1835x over previous
//
#include <hip/hip_runtime.h>
#include <hip/hip_bf16.h>

typedef __attribute__((ext_vector_type(8))) short   s16x8;
typedef __attribute__((ext_vector_type(8))) __bf16  bf16x8;
typedef __attribute__((ext_vector_type(4))) float   f32x4;

#define DEV static __device__ __forceinline__

DEV short f2bf(float f) {
  unsigned u = __builtin_bit_cast(unsigned, f);
  u = (u + 0x7fff + ((u >> 16) & 1)) >> 16;
  return (short)u;
}
DEV float bf2f(short s) {
  unsigned u = ((unsigned)(unsigned short)s) << 16;
  return __builtin_bit_cast(float, u);
}

DEV void gload16(const void* g, void* l) {
  __builtin_amdgcn_global_load_lds(
      (const __attribute__((address_space(1))) unsigned int*)g,
      (__attribute__((address_space(3))) unsigned int*)l, 16, 0, 0);
}

// ---------------- cast fp32 -> bf16, 8 elems/thread ----------------
__global__ __launch_bounds__(256) void cast8_kernel(const float* __restrict__ in,
                                                    short* __restrict__ out, long n) {
  long i = ((long)blockIdx.x * 256 + threadIdx.x) * 8;
  if (i >= n) return;
  float4 a = *(const float4*)(in + i);
  float4 b = *(const float4*)(in + i + 4);
  s16x8 o;
  o[0] = f2bf(a.x); o[1] = f2bf(a.y); o[2] = f2bf(a.z); o[3] = f2bf(a.w);
  o[4] = f2bf(b.x); o[5] = f2bf(b.y); o[6] = f2bf(b.z); o[7] = f2bf(b.w);
  *(s16x8*)(out + i) = o;
}

// ---------------- GEMM: C[M][N] = A[M][K] @ W[N][K]^T (bf16 in, fp32 acc) ---
// 128x128 tile, 4 waves (2x2), BK=32, global_load_lds staging (m97 pattern).
// MODE 0: plain fp32 C write (N=4096).  MODE 1: qkv split epilogue (N=6144),
//         vb written TRANSPOSED as [b][hkv][d][s] for flash's V^T staging.
template<int MODE>
__global__ __launch_bounds__(256) void gemm_bt(
    const short* __restrict__ A, const short* __restrict__ W,
    float* __restrict__ Cout,
    short* __restrict__ qb, short* __restrict__ kb, short* __restrict__ vb,
    float* __restrict__ nk, float* __restrict__ nv)
{
  const int K = 4096;
  __shared__ short As[128 * 32];
  __shared__ short Ws[128 * 32];
  const int tid = threadIdx.x;
  const int lane = tid & 63;
  const int w = tid >> 6;
  const int wm = w >> 1, wn = w & 1;
  const int tm = blockIdx.y, tn = blockIdx.x;
  const int l15 = lane & 15, koff = (lane >> 4) * 8;

  f32x4 zero = {0.f, 0.f, 0.f, 0.f};
  f32x4 acc[4][4];
  #pragma unroll
  for (int i = 0; i < 4; ++i)
    #pragma unroll
    for (int j = 0; j < 4; ++j) acc[i][j] = zero;

  const int e0 = tid * 8, e1 = tid * 8 + 2048;
  const int r0 = e0 >> 5, c0 = e0 & 31;
  const int r1 = e1 >> 5, c1 = e1 & 31;
  const long arow0 = (long)(tm * 128 + r0) * K;
  const long arow1 = (long)(tm * 128 + r1) * K;
  const long wrow0 = (long)(tn * 128 + r0) * K;
  const long wrow1 = (long)(tn * 128 + r1) * K;

  for (int k0 = 0; k0 < K; k0 += 32) {
    __syncthreads();
    gload16(&A[arow0 + k0 + c0], &As[e0]);
    gload16(&A[arow1 + k0 + c1], &As[e1]);
    gload16(&W[wrow0 + k0 + c0], &Ws[e0]);
    gload16(&W[wrow1 + k0 + c1], &Ws[e1]);
    __syncthreads();
    bf16x8 af[4], wf[4];
    #pragma unroll
    for (int i = 0; i < 4; ++i) {
      af[i] = *(const bf16x8*)&As[(wm * 64 + i * 16 + l15) * 32 + koff];
      wf[i] = *(const bf16x8*)&Ws[(wn * 64 + i * 16 + l15) * 32 + koff];
    }
    #pragma unroll
    for (int i = 0; i < 4; ++i)
      #pragma unroll
      for (int j = 0; j < 4; ++j)
        acc[i][j] = __builtin_amdgcn_mfma_f32_16x16x32_bf16(af[i], wf[j], acc[i][j], 0, 0, 0);
  }

  #pragma unroll
  for (int i = 0; i < 4; ++i) {
    int mbase = tm * 128 + wm * 64 + i * 16 + (lane >> 4) * 4;
    #pragma unroll
    for (int j = 0; j < 4; ++j) {
      int col = tn * 128 + wn * 64 + j * 16 + l15;
      #pragma unroll
      for (int r = 0; r < 4; ++r) {
        int m = mbase + r;
        float v = acc[i][j][r];
        if (MODE == 0) {
          Cout[(long)m * 4096 + col] = v;
        } else {
          int b = m >> 11, s = m & 2047;
          if (col < 4096) {
            int h = col >> 7, d = col & 127;
            qb[((long)((b * 32 + h) * 2048 + s)) * 128 + d] = f2bf(v);
          } else if (col < 5120) {
            int c2 = col - 4096;
            int h = c2 >> 7, d = c2 & 127;
            long o = ((long)((b * 8 + h) * 2048 + s)) * 128 + d;
            kb[o] = f2bf(v);
            nk[o] = v;
          } else {
            int c2 = col - 5120;
            int h = c2 >> 7, d = c2 & 127;
            long o = ((long)((b * 8 + h) * 2048 + s)) * 128 + d;
            nv[o] = v;
            // transposed bf16 V: [b][hkv][d][s]
            vb[((long)((b * 8 + h) * 128 + d)) * 2048 + s] = f2bf(v);
          }
        }
      }
    }
  }
}

// ---------------- RoPE in-place on q and k (bf16, interleaved pairs) --------
__global__ __launch_bounds__(256) void rope_kernel(short* __restrict__ qb,
                                                   short* __restrict__ kb) {
  const long QV = 2097152;  // q vectors of 8 elems
  const long TV = 2621440;  // + k vectors
  long i = (long)blockIdx.x * 256 + threadIdx.x;
  if (i >= TV) return;
  short* p;
  long e;
  if (i < QV) { e = i * 8; p = qb + e; }
  else        { e = (i - QV) * 8; p = kb + e; }
  int d0 = (int)(e & 127);
  int s  = (int)((e >> 7) & 2047);
  int jb = d0 >> 1;
  s16x8 v = *(const s16x8*)p;
  #pragma unroll
  for (int t = 0; t < 4; ++t) {
    float x1 = bf2f(v[2 * t]), x2 = bf2f(v[2 * t + 1]);
    int j = jb + t;
    float inv = __expf(-0.14391157f * (float)j);  // 10000^(-2j/128)
    float ang = (float)s * inv;
    float sn, cs;
    __sincosf(ang, &sn, &cs);
    v[2 * t]     = f2bf(x1 * cs - x2 * sn);
    v[2 * t + 1] = f2bf(x1 * sn + x2 * cs);
  }
  *(s16x8*)p = v;
}

// ---------------- Flash attention v2, causal, GQA 4:1 -----------------------
// grid (16, 32, 2), 256 thr = 4 waves; Q tile 128, wave = 32 q rows, KV = 64.
// K,V^T staged via global_load_lds with pre-swizzled source (XOR (row&7)<<4).
__global__ __launch_bounds__(256) void flash_kernel(
    const short* __restrict__ qb, const short* __restrict__ kb,
    const short* __restrict__ vt, short* __restrict__ ao)
{
  const int qt = 15 - blockIdx.x;  // heavy blocks first (causal imbalance)
  const int h = blockIdx.y, b = blockIdx.z;
  const int hkv = h >> 2;
  const int tid = threadIdx.x, w = tid >> 6, lane = tid & 63;
  const int l15 = lane & 15, lg = lane >> 4, koff = lg * 8;
  const int q0 = qt * 128 + w * 32;

  const short* Q  = qb + (long)(b * 32 + h) * 2048 * 128;
  const char*  Kg = (const char*)(kb + (long)(b * 8 + hkv) * 2048 * 128);
  const char*  Vg = (const char*)(vt + (long)(b * 8 + hkv) * 2048 * 128);  // [d][s]

  __shared__ short Ks[64 * 128];    // [kv][d], 16B chunks XOR-swizzled by kv&7
  __shared__ short Vs[128 * 64];    // [d][kv], 16B chunks XOR-swizzled by d&7
  __shared__ short Pl[4][32 * 64];  // per-wave P [ql][kv], swizzled by ql&7

  bf16x8 qf[2][4];
  #pragma unroll
  for (int i = 0; i < 2; ++i)
    #pragma unroll
    for (int ks = 0; ks < 4; ++ks)
      qf[i][ks] = *(const bf16x8*)&Q[(long)(q0 + i * 16 + l15) * 128 + ks * 32 + koff];

  f32x4 zero = {0.f, 0.f, 0.f, 0.f};
  f32x4 o[2][8];
  #pragma unroll
  for (int i = 0; i < 2; ++i)
    #pragma unroll
    for (int df = 0; df < 8; ++df) o[i][df] = zero;
  float m_[2][4], l_[2][4];
  #pragma unroll
  for (int i = 0; i < 2; ++i)
    #pragma unroll
    for (int r = 0; r < 4; ++r) { m_[i][r] = -3e38f; l_[i][r] = 0.f; }

  const float scale = 0.08838834764831845f;  // 1/sqrt(128)
  const int nt = 2 * (qt + 1);
  for (int t = 0; t < nt; ++t) {
    const int kv0 = t * 64;
    __syncthreads();
    // stage K (64x128, rows 256B) and V^T (128x64, rows 128B): linear LDS dest,
    // pre-swizzled global source (rule #21).
    #pragma unroll
    for (int i2 = 0; i2 < 4; ++i2) {
      int X = tid * 16 + i2 * 4096;
      int sk = X ^ (((X >> 8) & 7) << 4);
      gload16(Kg + (long)kv0 * 256 + sk, (char*)Ks + X);
      int sv = X ^ (((X >> 7) & 7) << 4);
      gload16(Vg + ((long)(sv >> 7) * 4096 + (long)kv0 * 2 + (sv & 127)), (char*)Vs + X);
    }
    __syncthreads();
    if (kv0 > q0 + 31) continue;  // fully-masked tile for this wave (barriers balanced)

    // S = Q K^T : 32 q x 64 kv
    f32x4 sc[2][4];
    #pragma unroll
    for (int i = 0; i < 2; ++i)
      #pragma unroll
      for (int jf = 0; jf < 4; ++jf) sc[i][jf] = zero;
    #pragma unroll
    for (int ks = 0; ks < 4; ++ks) {
      bf16x8 kf[4];
      #pragma unroll
      for (int jf = 0; jf < 4; ++jf) {
        int row = jf * 16 + l15;
        kf[jf] = *(const bf16x8*)((const char*)Ks + row * 256 +
                                  ((ks * 64 + lg * 16) ^ ((row & 7) << 4)));
      }
      #pragma unroll
      for (int i = 0; i < 2; ++i)
        #pragma unroll
        for (int jf = 0; jf < 4; ++jf)
          sc[i][jf] = __builtin_amdgcn_mfma_f32_16x16x32_bf16(qf[i][ks], kf[jf], sc[i][jf], 0, 0, 0);
    }

    // scale + causal mask + row max
    const bool diag = (kv0 + 63 > q0);  // wave-uniform
    float pm[2][4];
    int need = 0;
    #pragma unroll
    for (int i = 0; i < 2; ++i)
      #pragma unroll
      for (int r = 0; r < 4; ++r) {
        int q_abs = q0 + i * 16 + lg * 4 + r;
        #pragma unroll
        for (int jf = 0; jf < 4; ++jf) {
          float s = sc[i][jf][r] * scale;
          if (diag && (kv0 + jf * 16 + l15 > q_abs)) s = -3e38f;
          sc[i][jf][r] = s;
        }
        float mx = fmaxf(fmaxf(sc[i][0][r], sc[i][1][r]),
                         fmaxf(sc[i][2][r], sc[i][3][r]));
        mx = fmaxf(mx, __shfl_xor(mx, 1));
        mx = fmaxf(mx, __shfl_xor(mx, 2));
        mx = fmaxf(mx, __shfl_xor(mx, 4));
        mx = fmaxf(mx, __shfl_xor(mx, 8));
        pm[i][r] = mx;
        need |= (mx > m_[i][r] + 8.0f);
      }
    if (__any(need)) {  // T13 defer-max: rescale only when tile max grew >8
      #pragma unroll
      for (int i = 0; i < 2; ++i)
        #pragma unroll
        for (int r = 0; r < 4; ++r) {
          float mn = fmaxf(m_[i][r], pm[i][r]);
          float fac = __expf(m_[i][r] - mn);
          m_[i][r] = mn;
          l_[i][r] *= fac;
          #pragma unroll
          for (int df = 0; df < 8; ++df) o[i][df][r] *= fac;
        }
    }

    // P = exp(s-m): row sums + store to per-wave swizzled LDS
    #pragma unroll
    for (int i = 0; i < 2; ++i)
      #pragma unroll
      for (int r = 0; r < 4; ++r) {
        int ql = i * 16 + lg * 4 + r;
        float rs = 0.f;
        #pragma unroll
        for (int jf = 0; jf < 4; ++jf) {
          float p = __expf(sc[i][jf][r] - m_[i][r]);
          rs += p;
          int kv = jf * 16 + l15;
          *(short*)((char*)&Pl[w][0] + ql * 128 + ((kv * 2) ^ ((ql & 7) << 4))) = f2bf(p);
        }
        rs += __shfl_xor(rs, 1);
        rs += __shfl_xor(rs, 2);
        rs += __shfl_xor(rs, 4);
        rs += __shfl_xor(rs, 8);
        l_[i][r] += rs;
      }
    asm volatile("s_waitcnt lgkmcnt(0)" ::: "memory");
    __builtin_amdgcn_sched_barrier(0);

    // O += P V : per-wave, no barrier (Pl is wave-private)
    #pragma unroll
    for (int ks = 0; ks < 2; ++ks) {
      bf16x8 pa[2];
      #pragma unroll
      for (int i = 0; i < 2; ++i) {
        int ql = i * 16 + l15;
        pa[i] = *(const bf16x8*)((const char*)&Pl[w][0] + ql * 128 +
                                 ((ks * 64 + lg * 16) ^ ((ql & 7) << 4)));
      }
      #pragma unroll
      for (int df = 0; df < 8; ++df) {
        int dr = df * 16 + l15;
        bf16x8 vf = *(const bf16x8*)((const char*)Vs + dr * 128 +
                                     ((ks * 64 + lg * 16) ^ ((dr & 7) << 4)));
        #pragma unroll
        for (int i = 0; i < 2; ++i)
          o[i][df] = __builtin_amdgcn_mfma_f32_16x16x32_bf16(pa[i], vf, o[i][df], 0, 0, 0);
      }
    }
  }

  #pragma unroll
  for (int i = 0; i < 2; ++i)
    #pragma unroll
    for (int df = 0; df < 8; ++df) {
      int d = df * 16 + l15;
      #pragma unroll
      for (int r = 0; r < 4; ++r) {
        int qrow = q0 + i * 16 + lg * 4 + r;
        ao[((long)(b * 2048 + qrow)) * 4096 + h * 128 + d] = f2bf(o[i][df][r] / l_[i][r]);
      }
    }
}

// ---------------- launcher --------------------------------------------------
extern "C" void kernel_launch(void* const* d_in, const int* in_sizes, int n_in,
                              void* d_out, int out_size, void* d_ws, size_t ws_size,
                              hipStream_t stream) {
  const float* x  = (const float*)d_in[0];
  const float* wq = (const float*)d_in[1];
  const float* wk = (const float*)d_in[2];
  const float* wv = (const float*)d_in[3];
  const float* wo = (const float*)d_in[4];
  float* out = (float*)d_out;

  char* ws = (char*)d_ws;
  short* xb    = (short*)(ws);               // x bf16; later reused as attn_out
  short* wqkvb = (short*)(ws + 33554432);    // wq|wk|wv bf16 (6144x4096)
  short* wob   = (short*)(ws + 83886080);
  short* qb    = (short*)(ws + 117440512);   // (B,H,S,D)
  short* kb    = (short*)(ws + 150994944);   // (B,Hkv,S,D)
  short* vb    = (short*)(ws + 159383552);   // (B,Hkv,D,S)  TRANSPOSED
  short* ao    = xb;

  float* nk = out + 16777216;  // new_k fp32 (B,Hkv,S,D)
  float* nv = out + 20971520;  // new_v fp32

  cast8_kernel<<<8192, 256, 0, stream>>>(x,  xb,    16777216);
  cast8_kernel<<<8192, 256, 0, stream>>>(wq, wqkvb, 16777216);
  cast8_kernel<<<2048, 256, 0, stream>>>(wk, wqkvb + 16777216, 4194304);
  cast8_kernel<<<2048, 256, 0, stream>>>(wv, wqkvb + 20971520, 4194304);
  cast8_kernel<<<8192, 256, 0, stream>>>(wo, wob,   16777216);

  gemm_bt<1><<<dim3(48, 32), 256, 0, stream>>>(xb, wqkvb, nullptr, qb, kb, vb, nk, nv);
  rope_kernel<<<10240, 256, 0, stream>>>(qb, kb);
  flash_kernel<<<dim3(16, 32, 2), 256, 0, stream>>>(qb, kb, vb, ao);
  gemm_bt<0><<<dim3(32, 32), 256, 0, stream>>>(ao, wob, out, nullptr, nullptr, nullptr,
                                               nullptr, nullptr);
}

// Round 3
// 1029.899 us; speedup vs baseline: 1.2169x; 1.0282x over previous
//
#include <hip/hip_runtime.h>
#include <hip/hip_bf16.h>

typedef __attribute__((ext_vector_type(8))) short   s16x8;
typedef __attribute__((ext_vector_type(8))) __bf16  bf16x8;
typedef __attribute__((ext_vector_type(4))) float   f32x4;

#define DEV static __device__ __forceinline__

DEV short f2bf(float f) {
  unsigned u = __builtin_bit_cast(unsigned, f);
  u = (u + 0x7fff + ((u >> 16) & 1)) >> 16;
  return (short)u;
}
DEV float bf2f(short s) {
  unsigned u = ((unsigned)(unsigned short)s) << 16;
  return __builtin_bit_cast(float, u);
}

DEV void gload16(const void* g, void* l) {
  __builtin_amdgcn_global_load_lds(
      (const __attribute__((address_space(1))) unsigned int*)g,
      (__attribute__((address_space(3))) unsigned int*)l, 16, 0, 0);
}

// ---------------- cast fp32 -> bf16, 8 elems/thread ----------------
__global__ __launch_bounds__(256) void cast8_kernel(const float* __restrict__ in,
                                                    short* __restrict__ out, long n) {
  long i = ((long)blockIdx.x * 256 + threadIdx.x) * 8;
  if (i >= n) return;
  float4 a = *(const float4*)(in + i);
  float4 b = *(const float4*)(in + i + 4);
  s16x8 o;
  o[0] = f2bf(a.x); o[1] = f2bf(a.y); o[2] = f2bf(a.z); o[3] = f2bf(a.w);
  o[4] = f2bf(b.x); o[5] = f2bf(b.y); o[6] = f2bf(b.z); o[7] = f2bf(b.w);
  *(s16x8*)(out + i) = o;
}

// ---------------- GEMM: C[M][N] = A[M][K] @ W[N][K]^T (bf16 in, fp32 acc) ---
// 128x128 tile, 4 waves (2x2), BK=32, global_load_lds staging (m97 pattern).
// MODE 0: plain fp32 C write (N=4096).  MODE 1: qkv split epilogue (N=6144),
//         vb written TRANSPOSED as [b][hkv][d][s] for flash's V^T staging.
template<int MODE>
__global__ __launch_bounds__(256) void gemm_bt(
    const short* __restrict__ A, const short* __restrict__ W,
    float* __restrict__ Cout,
    short* __restrict__ qb, short* __restrict__ kb, short* __restrict__ vb,
    float* __restrict__ nk, float* __restrict__ nv)
{
  const int K = 4096;
  __shared__ short As[128 * 32];
  __shared__ short Ws[128 * 32];
  const int tid = threadIdx.x;
  const int lane = tid & 63;
  const int w = tid >> 6;
  const int wm = w >> 1, wn = w & 1;
  const int tm = blockIdx.y, tn = blockIdx.x;
  const int l15 = lane & 15, koff = (lane >> 4) * 8;

  f32x4 zero = {0.f, 0.f, 0.f, 0.f};
  f32x4 acc[4][4];
  #pragma unroll
  for (int i = 0; i < 4; ++i)
    #pragma unroll
    for (int j = 0; j < 4; ++j) acc[i][j] = zero;

  const int e0 = tid * 8, e1 = tid * 8 + 2048;
  const int r0 = e0 >> 5, c0 = e0 & 31;
  const int r1 = e1 >> 5, c1 = e1 & 31;
  const long arow0 = (long)(tm * 128 + r0) * K;
  const long arow1 = (long)(tm * 128 + r1) * K;
  const long wrow0 = (long)(tn * 128 + r0) * K;
  const long wrow1 = (long)(tn * 128 + r1) * K;

  for (int k0 = 0; k0 < K; k0 += 32) {
    __syncthreads();
    gload16(&A[arow0 + k0 + c0], &As[e0]);
    gload16(&A[arow1 + k0 + c1], &As[e1]);
    gload16(&W[wrow0 + k0 + c0], &Ws[e0]);
    gload16(&W[wrow1 + k0 + c1], &Ws[e1]);
    __syncthreads();
    bf16x8 af[4], wf[4];
    #pragma unroll
    for (int i = 0; i < 4; ++i) {
      af[i] = *(const bf16x8*)&As[(wm * 64 + i * 16 + l15) * 32 + koff];
      wf[i] = *(const bf16x8*)&Ws[(wn * 64 + i * 16 + l15) * 32 + koff];
    }
    #pragma unroll
    for (int i = 0; i < 4; ++i)
      #pragma unroll
      for (int j = 0; j < 4; ++j)
        acc[i][j] = __builtin_amdgcn_mfma_f32_16x16x32_bf16(af[i], wf[j], acc[i][j], 0, 0, 0);
  }

  #pragma unroll
  for (int i = 0; i < 4; ++i) {
    int mbase = tm * 128 + wm * 64 + i * 16 + (lane >> 4) * 4;
    #pragma unroll
    for (int j = 0; j < 4; ++j) {
      int col = tn * 128 + wn * 64 + j * 16 + l15;
      #pragma unroll
      for (int r = 0; r < 4; ++r) {
        int m = mbase + r;
        float v = acc[i][j][r];
        if (MODE == 0) {
          Cout[(long)m * 4096 + col] = v;
        } else {
          int b = m >> 11, s = m & 2047;
          if (col < 4096) {
            int h = col >> 7, d = col & 127;
            qb[((long)((b * 32 + h) * 2048 + s)) * 128 + d] = f2bf(v);
          } else if (col < 5120) {
            int c2 = col - 4096;
            int h = c2 >> 7, d = c2 & 127;
            long o = ((long)((b * 8 + h) * 2048 + s)) * 128 + d;
            kb[o] = f2bf(v);
            nk[o] = v;
          } else {
            int c2 = col - 5120;
            int h = c2 >> 7, d = c2 & 127;
            long o = ((long)((b * 8 + h) * 2048 + s)) * 128 + d;
            nv[o] = v;
            // transposed bf16 V: [b][hkv][d][s]
            vb[((long)((b * 8 + h) * 128 + d)) * 2048 + s] = f2bf(v);
          }
        }
      }
    }
  }
}

// ---------------- RoPE in-place on q and k (bf16, interleaved pairs) --------
__global__ __launch_bounds__(256) void rope_kernel(short* __restrict__ qb,
                                                   short* __restrict__ kb) {
  const long QV = 2097152;  // q vectors of 8 elems
  const long TV = 2621440;  // + k vectors
  long i = (long)blockIdx.x * 256 + threadIdx.x;
  if (i >= TV) return;
  short* p;
  long e;
  if (i < QV) { e = i * 8; p = qb + e; }
  else        { e = (i - QV) * 8; p = kb + e; }
  int d0 = (int)(e & 127);
  int s  = (int)((e >> 7) & 2047);
  int jb = d0 >> 1;
  s16x8 v = *(const s16x8*)p;
  #pragma unroll
  for (int t = 0; t < 4; ++t) {
    float x1 = bf2f(v[2 * t]), x2 = bf2f(v[2 * t + 1]);
    int j = jb + t;
    float inv = __expf(-0.14391157f * (float)j);  // 10000^(-2j/128)
    float ang = (float)s * inv;
    float sn, cs;
    __sincosf(ang, &sn, &cs);
    v[2 * t]     = f2bf(x1 * cs - x2 * sn);
    v[2 * t + 1] = f2bf(x1 * sn + x2 * cs);
  }
  *(s16x8*)p = v;
}

// ---------------- Flash attention v3: pipelined, causal, GQA 4:1 ------------
// grid (16, 32, 2), 256 thr = 4 waves; Q tile 128, wave = 32 q rows, KV = 64.
// Double-buffered K/V^T staged via global_load_lds (pre-swizzled source);
// STAGE(t+1) issued before compute(t) -> latency hides under compute (T3-min).
__global__ __launch_bounds__(256) void flash_kernel(
    const short* __restrict__ qb, const short* __restrict__ kb,
    const short* __restrict__ vt, short* __restrict__ ao)
{
  const int qt = 15 - blockIdx.x;  // heavy blocks first (causal imbalance)
  const int h = blockIdx.y, b = blockIdx.z;
  const int hkv = h >> 2;
  const int tid = threadIdx.x, w = tid >> 6, lane = tid & 63;
  const int l15 = lane & 15, lg = lane >> 4, koff = lg * 8;
  const int q0 = qt * 128 + w * 32;

  const short* Q  = qb + (long)(b * 32 + h) * 2048 * 128;
  const char*  Kg = (const char*)(kb + (long)(b * 8 + hkv) * 2048 * 128);
  const char*  Vg = (const char*)(vt + (long)(b * 8 + hkv) * 2048 * 128);  // [d][s]

  __shared__ short Ks[2][64 * 128];  // [kv][d], 16B chunks XOR-swizzled by kv&7
  __shared__ short Vs[2][128 * 64];  // [d][kv], 16B chunks XOR-swizzled by d&7
  __shared__ short Pl[4][32 * 64];   // per-wave P [ql][kv], swizzled by ql&7

  // precompute swizzled staging offsets (loop-invariant)
  int skX[4], svRow[4], svCol[4], Xo[4];
  #pragma unroll
  for (int i2 = 0; i2 < 4; ++i2) {
    int X = tid * 16 + i2 * 4096;
    Xo[i2] = X;
    skX[i2] = X ^ (((X >> 8) & 7) << 4);
    int sv = X ^ (((X >> 7) & 7) << 4);
    svRow[i2] = sv >> 7;
    svCol[i2] = sv & 127;
  }

  bf16x8 qf[2][4];
  #pragma unroll
  for (int i = 0; i < 2; ++i)
    #pragma unroll
    for (int ks = 0; ks < 4; ++ks)
      qf[i][ks] = *(const bf16x8*)&Q[(long)(q0 + i * 16 + l15) * 128 + ks * 32 + koff];

  f32x4 zero = {0.f, 0.f, 0.f, 0.f};
  f32x4 o[2][8];
  #pragma unroll
  for (int i = 0; i < 2; ++i)
    #pragma unroll
    for (int df = 0; df < 8; ++df) o[i][df] = zero;
  float m_[2][4], l_[2][4];
  #pragma unroll
  for (int i = 0; i < 2; ++i)
    #pragma unroll
    for (int r = 0; r < 4; ++r) { m_[i][r] = -3e38f; l_[i][r] = 0.f; }

  // scale folded with log2(e): softmax done in exp2 domain
  const float scale2 = 0.08838834764831845f * 1.4426950408889634f;
  const int nt = 2 * (qt + 1);

  // prologue: stage tile 0 into buffer 0
  #pragma unroll
  for (int i2 = 0; i2 < 4; ++i2) {
    gload16(Kg + skX[i2], (char*)Ks[0] + Xo[i2]);
    gload16(Vg + ((long)svRow[i2] * 4096 + svCol[i2]), (char*)Vs[0] + Xo[i2]);
  }

  for (int t = 0; t < nt; ++t) {
    const int kv0 = t * 64;
    const int cur = t & 1;
    __syncthreads();  // drains stage(t) (compiler vmcnt(0)) + syncs buffers
    if (t + 1 < nt) {  // issue stage(t+1) BEFORE compute(t): latency overlap
      const long kvb = (long)(kv0 + 64);
      #pragma unroll
      for (int i2 = 0; i2 < 4; ++i2) {
        gload16(Kg + kvb * 256 + skX[i2], (char*)Ks[cur ^ 1] + Xo[i2]);
        gload16(Vg + ((long)svRow[i2] * 4096 + kvb * 2 + svCol[i2]),
                (char*)Vs[cur ^ 1] + Xo[i2]);
      }
    }
    if (kv0 > q0 + 31) continue;  // fully-masked tile for this wave

    // S = Q K^T : 32 q x 64 kv
    f32x4 sc[2][4];
    #pragma unroll
    for (int i = 0; i < 2; ++i)
      #pragma unroll
      for (int jf = 0; jf < 4; ++jf) sc[i][jf] = zero;
    __builtin_amdgcn_s_setprio(1);
    #pragma unroll
    for (int ks = 0; ks < 4; ++ks) {
      bf16x8 kf[4];
      #pragma unroll
      for (int jf = 0; jf < 4; ++jf) {
        int row = jf * 16 + l15;
        kf[jf] = *(const bf16x8*)((const char*)Ks[cur] + row * 256 +
                                  ((ks * 64 + lg * 16) ^ ((row & 7) << 4)));
      }
      #pragma unroll
      for (int i = 0; i < 2; ++i)
        #pragma unroll
        for (int jf = 0; jf < 4; ++jf)
          sc[i][jf] = __builtin_amdgcn_mfma_f32_16x16x32_bf16(qf[i][ks], kf[jf], sc[i][jf], 0, 0, 0);
    }
    __builtin_amdgcn_s_setprio(0);

    // scale (exp2 domain) + causal mask (only on diagonal tiles) + row max
    const bool diag = (kv0 + 63 > q0);  // wave-uniform
    #pragma unroll
    for (int i = 0; i < 2; ++i)
      #pragma unroll
      for (int jf = 0; jf < 4; ++jf)
        #pragma unroll
        for (int r = 0; r < 4; ++r) sc[i][jf][r] *= scale2;
    if (diag) {
      #pragma unroll
      for (int i = 0; i < 2; ++i)
        #pragma unroll
        for (int r = 0; r < 4; ++r) {
          int q_abs = q0 + i * 16 + lg * 4 + r;
          #pragma unroll
          for (int jf = 0; jf < 4; ++jf)
            if (kv0 + jf * 16 + l15 > q_abs) sc[i][jf][r] = -3e38f;
        }
    }
    float pm[2][4];
    int need = 0;
    #pragma unroll
    for (int i = 0; i < 2; ++i)
      #pragma unroll
      for (int r = 0; r < 4; ++r) {
        float mx = fmaxf(fmaxf(sc[i][0][r], sc[i][1][r]),
                         fmaxf(sc[i][2][r], sc[i][3][r]));
        mx = fmaxf(mx, __shfl_xor(mx, 1));
        mx = fmaxf(mx, __shfl_xor(mx, 2));
        mx = fmaxf(mx, __shfl_xor(mx, 4));
        mx = fmaxf(mx, __shfl_xor(mx, 8));
        pm[i][r] = mx;
        need |= (mx > m_[i][r] + 11.5f);  // 8 nats in exp2 domain
      }
    if (__any(need)) {  // T13 defer-max
      #pragma unroll
      for (int i = 0; i < 2; ++i)
        #pragma unroll
        for (int r = 0; r < 4; ++r) {
          float mn = fmaxf(m_[i][r], pm[i][r]);
          float fac = exp2f(m_[i][r] - mn);
          m_[i][r] = mn;
          l_[i][r] *= fac;
          #pragma unroll
          for (int df = 0; df < 8; ++df) o[i][df][r] *= fac;
        }
    }

    // P = exp2(s-m): row sums + store to per-wave swizzled LDS
    #pragma unroll
    for (int i = 0; i < 2; ++i)
      #pragma unroll
      for (int r = 0; r < 4; ++r) {
        int ql = i * 16 + lg * 4 + r;
        float rs = 0.f;
        #pragma unroll
        for (int jf = 0; jf < 4; ++jf) {
          float p = exp2f(sc[i][jf][r] - m_[i][r]);
          rs += p;
          int kv = jf * 16 + l15;
          *(short*)((char*)&Pl[w][0] + ql * 128 + ((kv * 2) ^ ((ql & 7) << 4))) = f2bf(p);
        }
        rs += __shfl_xor(rs, 1);
        rs += __shfl_xor(rs, 2);
        rs += __shfl_xor(rs, 4);
        rs += __shfl_xor(rs, 8);
        l_[i][r] += rs;
      }
    asm volatile("s_waitcnt lgkmcnt(0)" ::: "memory");
    __builtin_amdgcn_sched_barrier(0);

    // O += P V : per-wave, no barrier (Pl is wave-private)
    __builtin_amdgcn_s_setprio(1);
    #pragma unroll
    for (int ks = 0; ks < 2; ++ks) {
      bf16x8 pa[2];
      #pragma unroll
      for (int i = 0; i < 2; ++i) {
        int ql = i * 16 + l15;
        pa[i] = *(const bf16x8*)((const char*)&Pl[w][0] + ql * 128 +
                                 ((ks * 64 + lg * 16) ^ ((ql & 7) << 4)));
      }
      #pragma unroll
      for (int df = 0; df < 8; ++df) {
        int dr = df * 16 + l15;
        bf16x8 vf = *(const bf16x8*)((const char*)Vs[cur] + dr * 128 +
                                     ((ks * 64 + lg * 16) ^ ((dr & 7) << 4)));
        #pragma unroll
        for (int i = 0; i < 2; ++i)
          o[i][df] = __builtin_amdgcn_mfma_f32_16x16x32_bf16(pa[i], vf, o[i][df], 0, 0, 0);
      }
    }
    __builtin_amdgcn_s_setprio(0);
  }

  #pragma unroll
  for (int i = 0; i < 2; ++i)
    #pragma unroll
    for (int df = 0; df < 8; ++df) {
      int d = df * 16 + l15;
      #pragma unroll
      for (int r = 0; r < 4; ++r) {
        int qrow = q0 + i * 16 + lg * 4 + r;
        ao[((long)(b * 2048 + qrow)) * 4096 + h * 128 + d] = f2bf(o[i][df][r] / l_[i][r]);
      }
    }
}

// ---------------- launcher --------------------------------------------------
extern "C" void kernel_launch(void* const* d_in, const int* in_sizes, int n_in,
                              void* d_out, int out_size, void* d_ws, size_t ws_size,
                              hipStream_t stream) {
  const float* x  = (const float*)d_in[0];
  const float* wq = (const float*)d_in[1];
  const float* wk = (const float*)d_in[2];
  const float* wv = (const float*)d_in[3];
  const float* wo = (const float*)d_in[4];
  float* out = (float*)d_out;

  char* ws = (char*)d_ws;
  short* xb    = (short*)(ws);               // x bf16; later reused as attn_out
  short* wqkvb = (short*)(ws + 33554432);    // wq|wk|wv bf16 (6144x4096)
  short* wob   = (short*)(ws + 83886080);
  short* qb    = (short*)(ws + 117440512);   // (B,H,S,D)
  short* kb    = (short*)(ws + 150994944);   // (B,Hkv,S,D)
  short* vb    = (short*)(ws + 159383552);   // (B,Hkv,D,S)  TRANSPOSED
  short* ao    = xb;

  float* nk = out + 16777216;  // new_k fp32 (B,Hkv,S,D)
  float* nv = out + 20971520;  // new_v fp32

  cast8_kernel<<<8192, 256, 0, stream>>>(x,  xb,    16777216);
  cast8_kernel<<<8192, 256, 0, stream>>>(wq, wqkvb, 16777216);
  cast8_kernel<<<2048, 256, 0, stream>>>(wk, wqkvb + 16777216, 4194304);
  cast8_kernel<<<2048, 256, 0, stream>>>(wv, wqkvb + 20971520, 4194304);
  cast8_kernel<<<8192, 256, 0, stream>>>(wo, wob,   16777216);

  gemm_bt<1><<<dim3(48, 32), 256, 0, stream>>>(xb, wqkvb, nullptr, qb, kb, vb, nk, nv);
  rope_kernel<<<10240, 256, 0, stream>>>(qb, kb);
  flash_kernel<<<dim3(16, 32, 2), 256, 0, stream>>>(qb, kb, vb, ao);
  gemm_bt<0><<<dim3(32, 32), 256, 0, stream>>>(ao, wob, out, nullptr, nullptr, nullptr,
                                               nullptr, nullptr);
}

// Round 4
// 900.799 us; speedup vs baseline: 1.3914x; 1.1433x over previous
//
#include <hip/hip_runtime.h>
#include <hip/hip_bf16.h>

typedef __attribute__((ext_vector_type(8)))  short   s16x8;
typedef __attribute__((ext_vector_type(8)))  __bf16  bf16x8;
typedef __attribute__((ext_vector_type(4)))  float   f32x4;
typedef __attribute__((ext_vector_type(16))) float   f32x16;

#define DEV static __device__ __forceinline__

DEV short f2bf(float f) {
  unsigned u = __builtin_bit_cast(unsigned, f);
  u = (u + 0x7fff + ((u >> 16) & 1)) >> 16;
  return (short)u;
}
DEV float bf2f(short s) {
  unsigned u = ((unsigned)(unsigned short)s) << 16;
  return __builtin_bit_cast(float, u);
}

DEV void gload16(const void* g, void* l) {
  __builtin_amdgcn_global_load_lds(
      (const __attribute__((address_space(1))) unsigned int*)g,
      (__attribute__((address_space(3))) unsigned int*)l, 16, 0, 0);
}

DEV unsigned cvtpk(float lo, float hi) {  // bf16(lo) in low half, bf16(hi) in high
  unsigned r;
  asm("v_cvt_pk_bf16_f32 %0, %1, %2" : "=v"(r) : "v"(lo), "v"(hi));
  return r;
}

typedef union { unsigned u[4]; bf16x8 v; } BW;

// ---------------- cast fp32 -> bf16, 8 elems/thread ----------------
__global__ __launch_bounds__(256) void cast8_kernel(const float* __restrict__ in,
                                                    short* __restrict__ out, long n) {
  long i = ((long)blockIdx.x * 256 + threadIdx.x) * 8;
  if (i >= n) return;
  float4 a = *(const float4*)(in + i);
  float4 b = *(const float4*)(in + i + 4);
  s16x8 o;
  o[0] = f2bf(a.x); o[1] = f2bf(a.y); o[2] = f2bf(a.z); o[3] = f2bf(a.w);
  o[4] = f2bf(b.x); o[5] = f2bf(b.y); o[6] = f2bf(b.z); o[7] = f2bf(b.w);
  *(s16x8*)(out + i) = o;
}

// ---------------- GEMM: C[M][N] = A[M][K] @ W[N][K]^T (bf16 in, fp32 acc) ---
// 128x128 tile, 4 waves (2x2), BK=32, global_load_lds staging (m97 pattern).
template<int MODE>
__global__ __launch_bounds__(256) void gemm_bt(
    const short* __restrict__ A, const short* __restrict__ W,
    float* __restrict__ Cout,
    short* __restrict__ qb, short* __restrict__ kb, short* __restrict__ vb,
    float* __restrict__ nk, float* __restrict__ nv)
{
  const int K = 4096;
  __shared__ short As[128 * 32];
  __shared__ short Ws[128 * 32];
  const int tid = threadIdx.x;
  const int lane = tid & 63;
  const int w = tid >> 6;
  const int wm = w >> 1, wn = w & 1;
  const int tm = blockIdx.y, tn = blockIdx.x;
  const int l15 = lane & 15, koff = (lane >> 4) * 8;

  f32x4 zero = {0.f, 0.f, 0.f, 0.f};
  f32x4 acc[4][4];
  #pragma unroll
  for (int i = 0; i < 4; ++i)
    #pragma unroll
    for (int j = 0; j < 4; ++j) acc[i][j] = zero;

  const int e0 = tid * 8, e1 = tid * 8 + 2048;
  const int r0 = e0 >> 5, c0 = e0 & 31;
  const int r1 = e1 >> 5, c1 = e1 & 31;
  const long arow0 = (long)(tm * 128 + r0) * K;
  const long arow1 = (long)(tm * 128 + r1) * K;
  const long wrow0 = (long)(tn * 128 + r0) * K;
  const long wrow1 = (long)(tn * 128 + r1) * K;

  for (int k0 = 0; k0 < K; k0 += 32) {
    __syncthreads();
    gload16(&A[arow0 + k0 + c0], &As[e0]);
    gload16(&A[arow1 + k0 + c1], &As[e1]);
    gload16(&W[wrow0 + k0 + c0], &Ws[e0]);
    gload16(&W[wrow1 + k0 + c1], &Ws[e1]);
    __syncthreads();
    bf16x8 af[4], wf[4];
    #pragma unroll
    for (int i = 0; i < 4; ++i) {
      af[i] = *(const bf16x8*)&As[(wm * 64 + i * 16 + l15) * 32 + koff];
      wf[i] = *(const bf16x8*)&Ws[(wn * 64 + i * 16 + l15) * 32 + koff];
    }
    #pragma unroll
    for (int i = 0; i < 4; ++i)
      #pragma unroll
      for (int j = 0; j < 4; ++j)
        acc[i][j] = __builtin_amdgcn_mfma_f32_16x16x32_bf16(af[i], wf[j], acc[i][j], 0, 0, 0);
  }

  #pragma unroll
  for (int i = 0; i < 4; ++i) {
    int mbase = tm * 128 + wm * 64 + i * 16 + (lane >> 4) * 4;
    #pragma unroll
    for (int j = 0; j < 4; ++j) {
      int col = tn * 128 + wn * 64 + j * 16 + l15;
      #pragma unroll
      for (int r = 0; r < 4; ++r) {
        int m = mbase + r;
        float v = acc[i][j][r];
        if (MODE == 0) {
          Cout[(long)m * 4096 + col] = v;
        } else {
          int b = m >> 11, s = m & 2047;
          if (col < 4096) {
            int h = col >> 7, d = col & 127;
            qb[((long)((b * 32 + h) * 2048 + s)) * 128 + d] = f2bf(v);
          } else if (col < 5120) {
            int c2 = col - 4096;
            int h = c2 >> 7, d = c2 & 127;
            long o = ((long)((b * 8 + h) * 2048 + s)) * 128 + d;
            kb[o] = f2bf(v);
            nk[o] = v;
          } else {
            int c2 = col - 5120;
            int h = c2 >> 7, d = c2 & 127;
            long o = ((long)((b * 8 + h) * 2048 + s)) * 128 + d;
            nv[o] = v;
            vb[((long)((b * 8 + h) * 128 + d)) * 2048 + s] = f2bf(v);  // [b][hkv][d][s]
          }
        }
      }
    }
  }
}

// ---------------- RoPE in-place on q and k (bf16, interleaved pairs) --------
__global__ __launch_bounds__(256) void rope_kernel(short* __restrict__ qb,
                                                   short* __restrict__ kb) {
  const long QV = 2097152;
  const long TV = 2621440;
  long i = (long)blockIdx.x * 256 + threadIdx.x;
  if (i >= TV) return;
  short* p;
  long e;
  if (i < QV) { e = i * 8; p = qb + e; }
  else        { e = (i - QV) * 8; p = kb + e; }
  int d0 = (int)(e & 127);
  int s  = (int)((e >> 7) & 2047);
  int jb = d0 >> 1;
  s16x8 v = *(const s16x8*)p;
  #pragma unroll
  for (int t = 0; t < 4; ++t) {
    float x1 = bf2f(v[2 * t]), x2 = bf2f(v[2 * t + 1]);
    int j = jb + t;
    float inv = __expf(-0.14391157f * (float)j);  // 10000^(-2j/128)
    float ang = (float)s * inv;
    float sn, cs;
    __sincosf(ang, &sn, &cs);
    v[2 * t]     = f2bf(x1 * cs - x2 * sn);
    v[2 * t + 1] = f2bf(x1 * sn + x2 * cs);
  }
  *(s16x8*)p = v;
}

// ---------------- Flash attention v4: swapped-QK in-register softmax --------
// grid (16, 32, 2), 256 thr = 4 waves; Q tile 128, wave = 32 q rows, KV = 64.
// 32x32x16 MFMA. S^T = mfma(K,Q): lane owns q = lane&31 (m_, l_ scalar/lane).
// P packed to bf16 in-register (cvt_pk + shfl_xor(32)); O^T = mfma(V^T, P^T).
__global__ __launch_bounds__(256) void flash_kernel(
    const short* __restrict__ qb, const short* __restrict__ kb,
    const short* __restrict__ vt, short* __restrict__ ao)
{
  const int qt = 15 - blockIdx.x;  // heavy blocks first (causal imbalance)
  const int h = blockIdx.y, b = blockIdx.z;
  const int hkv = h >> 2;
  const int tid = threadIdx.x, w = tid >> 6, lane = tid & 63;
  const int l31 = lane & 31, hi = lane >> 5;
  const int hi16 = hi * 16;             // byte offset of lane's k-half
  const int q0 = qt * 128 + w * 32;
  const int q_abs = q0 + l31;           // this lane's q row

  const short* Q  = qb + (long)(b * 32 + h) * 2048 * 128;
  const char*  Kg = (const char*)(kb + (long)(b * 8 + hkv) * 2048 * 128);
  const char*  Vg = (const char*)(vt + (long)(b * 8 + hkv) * 2048 * 128);  // [d][s]

  __shared__ short Ks[2][64 * 128];  // [kv][d], 16B chunks XOR-swizzled by kv&7
  __shared__ short Vs[2][128 * 64];  // [d][kv], 16B chunks XOR-swizzled by d&7

  // staging offsets (loop-invariant, pre-swizzled source per rule #21)
  int skX[4], svRow[4], svCol[4], Xo[4];
  #pragma unroll
  for (int i2 = 0; i2 < 4; ++i2) {
    int X = tid * 16 + i2 * 4096;
    Xo[i2] = X;
    skX[i2] = X ^ (((X >> 8) & 7) << 4);
    int sv = X ^ (((X >> 7) & 7) << 4);
    svRow[i2] = sv >> 7;
    svCol[i2] = sv & 127;
  }

  // Q fragments (B-operand): lane holds Q[q_abs][c*16 + hi*8 .. +7]
  bf16x8 qf[8];
  #pragma unroll
  for (int c = 0; c < 8; ++c)
    qf[c] = *(const bf16x8*)&Q[(long)q_abs * 128 + c * 16 + hi * 8];

  f32x16 o[4];
  #pragma unroll
  for (int db = 0; db < 4; ++db)
    #pragma unroll
    for (int r = 0; r < 16; ++r) o[db][r] = 0.f;
  float m_ = -3e38f, l_ = 0.f;

  const float scale2 = 0.08838834764831845f * 1.4426950408889634f;  // /sqrt(d)*log2e
  const int nt = 2 * (qt + 1);
  const int ksw = (l31 & 7) << 4;

  // prologue: stage tile 0 into buffer 0
  #pragma unroll
  for (int i2 = 0; i2 < 4; ++i2) {
    gload16(Kg + skX[i2], (char*)Ks[0] + Xo[i2]);
    gload16(Vg + ((long)svRow[i2] * 4096 + svCol[i2]), (char*)Vs[0] + Xo[i2]);
  }

  for (int t = 0; t < nt; ++t) {
    const int kv0 = t * 64;
    const int cur = t & 1;
    __syncthreads();  // drains stage(t); syncs buffer swap
    if (t + 1 < nt) {  // stage(t+1) issued before compute(t)
      const long kvb = (long)(kv0 + 64);
      #pragma unroll
      for (int i2 = 0; i2 < 4; ++i2) {
        gload16(Kg + kvb * 256 + skX[i2], (char*)Ks[cur ^ 1] + Xo[i2]);
        gload16(Vg + ((long)svRow[i2] * 4096 + kvb * 2 + svCol[i2]),
                (char*)Vs[cur ^ 1] + Xo[i2]);
      }
    }
    if (kv0 > q0 + 31) continue;  // fully-masked tile for this wave

    // ---- S^T = K · Q^T : two 32-kv sub-tiles, contracted over d=128 ----
    f32x16 s0, s1;
    #pragma unroll
    for (int r = 0; r < 16; ++r) { s0[r] = 0.f; s1[r] = 0.f; }
    const char* kbase = (const char*)Ks[cur] + l31 * 256;
    __builtin_amdgcn_s_setprio(1);
    #pragma unroll
    for (int c = 0; c < 8; ++c) {
      bf16x8 kf0 = *(const bf16x8*)(kbase + ((c * 32 + hi16) ^ ksw));
      bf16x8 kf1 = *(const bf16x8*)(kbase + 8192 + ((c * 32 + hi16) ^ ksw));
      s0 = __builtin_amdgcn_mfma_f32_32x32x16_bf16(kf0, qf[c], s0, 0, 0, 0);
      s1 = __builtin_amdgcn_mfma_f32_32x32x16_bf16(kf1, qf[c], s1, 0, 0, 0);
    }
    __builtin_amdgcn_s_setprio(0);

    // ---- softmax, fully per-lane (lane owns q row) ----
    const bool diag = (kv0 + 63 > q0);  // wave-uniform; only last computed tile
    if (diag) {
      #pragma unroll
      for (int r = 0; r < 16; ++r) {
        int krow = (r & 3) + 8 * (r >> 2) + 4 * hi;
        if (kv0 + krow > q_abs)      s0[r] = -3e38f;
        if (kv0 + 32 + krow > q_abs) s1[r] = -3e38f;
      }
    }
    float mx = fmaxf(s0[0], s1[0]);
    #pragma unroll
    for (int r = 1; r < 16; ++r) mx = fmaxf(mx, fmaxf(s0[r], s1[r]));
    mx *= scale2;
    mx = fmaxf(mx, __shfl_xor(mx, 32));
    int need = mx > m_ + 11.5f;  // 8 nats in exp2 domain
    if (__any(need)) {           // T13 defer-max
      float mn = fmaxf(m_, mx);
      float fac = exp2f(m_ - mn);
      m_ = mn;
      l_ *= fac;
      #pragma unroll
      for (int db = 0; db < 4; ++db)
        #pragma unroll
        for (int r = 0; r < 16; ++r) o[db][r] *= fac;
    }
    float rs = 0.f;
    #pragma unroll
    for (int r = 0; r < 16; ++r) {
      float p0 = exp2f(fmaf(s0[r], scale2, -m_));
      float p1 = exp2f(fmaf(s1[r], scale2, -m_));
      s0[r] = p0; s1[r] = p1;
      rs += p0 + p1;
    }
    rs += __shfl_xor(rs, 32);
    l_ += rs;

    // ---- O^T += V^T · P^T : P packed to bf16 in-register ----
    const char* vbase = (const char*)Vs[cur] + l31 * 128;
    #pragma unroll
    for (int t2 = 0; t2 < 2; ++t2) {
      const f32x16 sp = t2 ? s1 : s0;  // unrolled: folds to register alias
      unsigned wd[8];
      #pragma unroll
      for (int j = 0; j < 8; ++j) wd[j] = cvtpk(sp[2 * j], sp[2 * j + 1]);
      // exchange halves between lane and lane^32 (partner holds the other 4 kv rows)
      unsigned u0 = hi ? wd[0] : wd[2];
      unsigned u1 = hi ? wd[1] : wd[3];
      unsigned u2 = hi ? wd[4] : wd[6];
      unsigned u3 = hi ? wd[5] : wd[7];
      unsigned x0 = (unsigned)__shfl_xor((int)u0, 32);
      unsigned x1 = (unsigned)__shfl_xor((int)u1, 32);
      unsigned x2 = (unsigned)__shfl_xor((int)u2, 32);
      unsigned x3 = (unsigned)__shfl_xor((int)u3, 32);
      BW f0, f1;
      f0.u[0] = hi ? x0 : wd[0];
      f0.u[1] = hi ? x1 : wd[1];
      f0.u[2] = hi ? wd[2] : x0;
      f0.u[3] = hi ? wd[3] : x1;
      f1.u[0] = hi ? x2 : wd[4];
      f1.u[1] = hi ? x3 : wd[5];
      f1.u[2] = hi ? wd[6] : x2;
      f1.u[3] = hi ? wd[7] : x3;
      __builtin_amdgcn_s_setprio(1);
      #pragma unroll
      for (int cc = 0; cc < 2; ++cc) {
        const BW& fr = cc ? f1 : f0;
        #pragma unroll
        for (int db = 0; db < 4; ++db) {
          bf16x8 vf = *(const bf16x8*)(vbase + db * 4096 +
                                       ((t2 * 64 + cc * 32 + hi16) ^ ksw));
          o[db] = __builtin_amdgcn_mfma_f32_32x32x16_bf16(vf, fr.v, o[db], 0, 0, 0);
        }
      }
      __builtin_amdgcn_s_setprio(0);
    }
  }

  // ---- epilogue: O^T[d][q] -> ao[b][q][h*128+d], divide by l (lane-local) --
  float invl = 1.0f / l_;
  const long aorow = ((long)(b * 2048 + q_abs)) * 4096 + h * 128 + hi * 4;
  #pragma unroll
  for (int db = 0; db < 4; ++db)
    #pragma unroll
    for (int r = 0; r < 16; ++r) {
      int doff = db * 32 + (r & 3) + 8 * (r >> 2);
      ao[aorow + doff] = f2bf(o[db][r] * invl);
    }
}

// ---------------- launcher --------------------------------------------------
extern "C" void kernel_launch(void* const* d_in, const int* in_sizes, int n_in,
                              void* d_out, int out_size, void* d_ws, size_t ws_size,
                              hipStream_t stream) {
  const float* x  = (const float*)d_in[0];
  const float* wq = (const float*)d_in[1];
  const float* wk = (const float*)d_in[2];
  const float* wv = (const float*)d_in[3];
  const float* wo = (const float*)d_in[4];
  float* out = (float*)d_out;

  char* ws = (char*)d_ws;
  short* xb    = (short*)(ws);               // x bf16; later reused as attn_out
  short* wqkvb = (short*)(ws + 33554432);    // wq|wk|wv bf16 (6144x4096)
  short* wob   = (short*)(ws + 83886080);
  short* qb    = (short*)(ws + 117440512);   // (B,H,S,D)
  short* kb    = (short*)(ws + 150994944);   // (B,Hkv,S,D)
  short* vb    = (short*)(ws + 159383552);   // (B,Hkv,D,S)  TRANSPOSED
  short* ao    = xb;

  float* nk = out + 16777216;  // new_k fp32 (B,Hkv,S,D)
  float* nv = out + 20971520;  // new_v fp32

  cast8_kernel<<<8192, 256, 0, stream>>>(x,  xb,    16777216);
  cast8_kernel<<<8192, 256, 0, stream>>>(wq, wqkvb, 16777216);
  cast8_kernel<<<2048, 256, 0, stream>>>(wk, wqkvb + 16777216, 4194304);
  cast8_kernel<<<2048, 256, 0, stream>>>(wv, wqkvb + 20971520, 4194304);
  cast8_kernel<<<8192, 256, 0, stream>>>(wo, wob,   16777216);

  gemm_bt<1><<<dim3(48, 32), 256, 0, stream>>>(xb, wqkvb, nullptr, qb, kb, vb, nk, nv);
  rope_kernel<<<10240, 256, 0, stream>>>(qb, kb);
  flash_kernel<<<dim3(16, 32, 2), 256, 0, stream>>>(qb, kb, vb, ao);
  gemm_bt<0><<<dim3(32, 32), 256, 0, stream>>>(ao, wob, out, nullptr, nullptr, nullptr,
                                               nullptr, nullptr);
}

// Round 5
// 793.349 us; speedup vs baseline: 1.5798x; 1.1354x over previous
//
#include <hip/hip_runtime.h>
#include <hip/hip_bf16.h>

typedef __attribute__((ext_vector_type(8)))  short   s16x8;
typedef __attribute__((ext_vector_type(8)))  __bf16  bf16x8;
typedef __attribute__((ext_vector_type(4)))  float   f32x4;
typedef __attribute__((ext_vector_type(16))) float   f32x16;

#define DEV static __device__ __forceinline__

DEV short f2bf(float f) {
  unsigned u = __builtin_bit_cast(unsigned, f);
  u = (u + 0x7fff + ((u >> 16) & 1)) >> 16;
  return (short)u;
}
DEV float bf2f(short s) {
  unsigned u = ((unsigned)(unsigned short)s) << 16;
  return __builtin_bit_cast(float, u);
}

DEV void gload16(const void* g, void* l) {
  __builtin_amdgcn_global_load_lds(
      (const __attribute__((address_space(1))) unsigned int*)g,
      (__attribute__((address_space(3))) unsigned int*)l, 16, 0, 0);
}

DEV unsigned cvtpk(float lo, float hi) {
  unsigned r;
  asm("v_cvt_pk_bf16_f32 %0, %1, %2" : "=v"(r) : "v"(lo), "v"(hi));
  return r;
}

typedef union { unsigned u[4]; bf16x8 v; } BW;

// ---------------- cast fp32 -> bf16, 8 elems/thread ----------------
__global__ __launch_bounds__(256) void cast8_kernel(const float* __restrict__ in,
                                                    short* __restrict__ out, long n) {
  long i = ((long)blockIdx.x * 256 + threadIdx.x) * 8;
  if (i >= n) return;
  float4 a = *(const float4*)(in + i);
  float4 b = *(const float4*)(in + i + 4);
  s16x8 o;
  o[0] = f2bf(a.x); o[1] = f2bf(a.y); o[2] = f2bf(a.z); o[3] = f2bf(a.w);
  o[4] = f2bf(b.x); o[5] = f2bf(b.y); o[6] = f2bf(b.z); o[7] = f2bf(b.w);
  *(s16x8*)(out + i) = o;
}

// ---------------- GEMM 256x256, 8 waves, BK=64, deep-pipelined --------------
// C[M][N] = A[M][K] @ W[N][K]^T, bf16 in, fp32 acc. K=4096 fixed.
// LDS: 2 buffers x (A 256x64 + B 256x64), XOR-swizzled ((row&7)<<4) via
// pre-swizzled global source (rule #21). Counted vmcnt(8) at tile boundary
// (never drains to 0 mid-loop). Raw s_barrier only. T1 XCD swizzle on grid.
// MODE 0: fp32 C write (N=4096). MODE 1: qkv split epilogue (N=6144).
template<int MODE>
__global__ __launch_bounds__(512, 2) void gemm256(
    const short* __restrict__ A, const short* __restrict__ W,
    float* __restrict__ Cout,
    short* __restrict__ qb, short* __restrict__ kb, short* __restrict__ vb,
    float* __restrict__ nk, float* __restrict__ nv)
{
  const int K = 4096;
  __shared__ short lds[2][2][256 * 64];  // [buf][0=A,1=B]

  const int tid = threadIdx.x;
  const int lane = tid & 63;
  const int w = tid >> 6;
  const int wm = w >> 2, wn = w & 3;          // 2 x 4 waves
  const int l15 = lane & 15, lg = lane >> 4;
  const int swz = (l15 & 7) << 4;

  // T1: bijective XCD swizzle (grid size divisible by 8 in both launches)
  const int NTN = gridDim.x;
  int nwg = gridDim.x * gridDim.y;
  int orig = blockIdx.y * gridDim.x + blockIdx.x;
  int cpx = nwg >> 3;
  int snew = (orig & 7) * cpx + (orig >> 3);
  const int tn = snew % NTN, tm = snew / NTN;

  const char* Ac = (const char*)A;
  const char* Wc = (const char*)W;

  // per-thread staging: dest X linear, source col pre-swizzled
  int Xl[4];
  long abase[4], bbase[4];
  #pragma unroll
  for (int l4 = 0; l4 < 4; ++l4) {
    int X = tid * 16 + l4 * 8192;
    int row = X >> 7;
    int colS = (X & 127) ^ (((X >> 7) & 7) << 4);
    Xl[l4] = X;
    abase[l4] = (long)(tm * 256 + row) * 8192 + colS;
    bbase[l4] = (long)(tn * 256 + row) * 8192 + colS;
  }

#define STAGE(tt, bb)                                                       \
  {                                                                         \
    const long kof_ = (long)(tt) * 128;                                     \
    _Pragma("unroll")                                                       \
    for (int l4 = 0; l4 < 4; ++l4)                                          \
      gload16(Ac + abase[l4] + kof_, (char*)&lds[bb][0][0] + Xl[l4]);       \
    _Pragma("unroll")                                                       \
    for (int l4 = 0; l4 < 4; ++l4)                                          \
      gload16(Wc + bbase[l4] + kof_, (char*)&lds[bb][1][0] + Xl[l4]);       \
  }

  f32x4 zero = {0.f, 0.f, 0.f, 0.f};
  f32x4 acc[8][4];
  #pragma unroll
  for (int i = 0; i < 8; ++i)
    #pragma unroll
    for (int j = 0; j < 4; ++j) acc[i][j] = zero;

  // fragment read offsets (row&7 == l15&7, invariant)
  const int aro = (wm * 128 + l15) * 128;          // byte row base (A)
  const int bro = (wn * 64 + l15) * 128;           // byte row base (B)
  const int cs0 = ((0 << 6) | (lg << 4)) ^ swz;    // khalf 0 col bytes
  const int cs1 = ((1 << 6) | (lg << 4)) ^ swz;    // khalf 1 col bytes

  // prologue: stage tiles 0,1; wait tile 0
  STAGE(0, 0)
  STAGE(1, 1)
  asm volatile("s_waitcnt vmcnt(8)" ::: "memory");
  __builtin_amdgcn_s_barrier();

  for (int t = 0; t < 64; ++t) {
    const int bt = t & 1;
    const char* LA = (const char*)&lds[bt][0][0];
    const char* LB = (const char*)&lds[bt][1][0];

    // phase 0 reads all B-frags + A-frags mr0,1
    bf16x8 bfr[4][2];
    #pragma unroll
    for (int nr = 0; nr < 4; ++nr) {
      bfr[nr][0] = *(const bf16x8*)(LB + bro + nr * 2048 + cs0);
      bfr[nr][1] = *(const bf16x8*)(LB + bro + nr * 2048 + cs1);
    }
    #pragma unroll
    for (int p = 0; p < 4; ++p) {
      bf16x8 af[2][2];
      #pragma unroll
      for (int mi = 0; mi < 2; ++mi) {
        af[mi][0] = *(const bf16x8*)(LA + aro + (2 * p + mi) * 2048 + cs0);
        af[mi][1] = *(const bf16x8*)(LA + aro + (2 * p + mi) * 2048 + cs1);
      }
      __builtin_amdgcn_s_barrier();
      asm volatile("s_waitcnt lgkmcnt(0)" ::: "memory");
      __builtin_amdgcn_sched_barrier(0);
      __builtin_amdgcn_s_setprio(1);
      #pragma unroll
      for (int mi = 0; mi < 2; ++mi)
        #pragma unroll
        for (int nr = 0; nr < 4; ++nr) {
          acc[2 * p + mi][nr] = __builtin_amdgcn_mfma_f32_16x16x32_bf16(
              af[mi][0], bfr[nr][0], acc[2 * p + mi][nr], 0, 0, 0);
          acc[2 * p + mi][nr] = __builtin_amdgcn_mfma_f32_16x16x32_bf16(
              af[mi][1], bfr[nr][1], acc[2 * p + mi][nr], 0, 0, 0);
        }
      __builtin_amdgcn_s_setprio(0);
      __builtin_amdgcn_s_barrier();
    }
    // boundary: all reads of buf bt done (phase-3 barrier) -> refill it
    if (t < 62) {
      STAGE(t + 2, bt)
      asm volatile("s_waitcnt vmcnt(8)" ::: "memory");  // tile t+1 landed
      __builtin_amdgcn_s_barrier();
    } else if (t == 62) {
      asm volatile("s_waitcnt vmcnt(0)" ::: "memory");  // tile 63 landed
      __builtin_amdgcn_s_barrier();
    }
  }
#undef STAGE

  // epilogue
  #pragma unroll
  for (int mr = 0; mr < 8; ++mr) {
    int mbase = tm * 256 + wm * 128 + mr * 16 + lg * 4;
    #pragma unroll
    for (int nr = 0; nr < 4; ++nr) {
      int col = tn * 256 + wn * 64 + nr * 16 + l15;
      #pragma unroll
      for (int r = 0; r < 4; ++r) {
        int m = mbase + r;
        float v = acc[mr][nr][r];
        if (MODE == 0) {
          Cout[(long)m * 4096 + col] = v;
        } else {
          int b = m >> 11, s = m & 2047;
          if (col < 4096) {
            int h = col >> 7, d = col & 127;
            qb[((long)((b * 32 + h) * 2048 + s)) * 128 + d] = f2bf(v);
          } else if (col < 5120) {
            int c2 = col - 4096;
            int h = c2 >> 7, d = c2 & 127;
            long o = ((long)((b * 8 + h) * 2048 + s)) * 128 + d;
            kb[o] = f2bf(v);
            nk[o] = v;
          } else {
            int c2 = col - 5120;
            int h = c2 >> 7, d = c2 & 127;
            long o = ((long)((b * 8 + h) * 2048 + s)) * 128 + d;
            nv[o] = v;
            vb[((long)((b * 8 + h) * 128 + d)) * 2048 + s] = f2bf(v);  // [b][hkv][d][s]
          }
        }
      }
    }
  }
}

// ---------------- RoPE in-place on q and k (bf16, interleaved pairs) --------
__global__ __launch_bounds__(256) void rope_kernel(short* __restrict__ qb,
                                                   short* __restrict__ kb) {
  const long QV = 2097152;
  const long TV = 2621440;
  long i = (long)blockIdx.x * 256 + threadIdx.x;
  if (i >= TV) return;
  short* p;
  long e;
  if (i < QV) { e = i * 8; p = qb + e; }
  else        { e = (i - QV) * 8; p = kb + e; }
  int d0 = (int)(e & 127);
  int s  = (int)((e >> 7) & 2047);
  int jb = d0 >> 1;
  s16x8 v = *(const s16x8*)p;
  #pragma unroll
  for (int t = 0; t < 4; ++t) {
    float x1 = bf2f(v[2 * t]), x2 = bf2f(v[2 * t + 1]);
    int j = jb + t;
    float inv = __expf(-0.14391157f * (float)j);  // 10000^(-2j/128)
    float ang = (float)s * inv;
    float sn, cs;
    __sincosf(ang, &sn, &cs);
    v[2 * t]     = f2bf(x1 * cs - x2 * sn);
    v[2 * t + 1] = f2bf(x1 * sn + x2 * cs);
  }
  *(s16x8*)p = v;
}

// ---------------- Flash attention v4: swapped-QK in-register softmax --------
// grid (16, 32, 2), 256 thr = 4 waves; Q tile 128, wave = 32 q rows, KV = 64.
// 32x32x16 MFMA. S^T = mfma(K,Q): lane owns q = lane&31 (m_, l_ scalar/lane).
// P packed to bf16 in-register (cvt_pk + shfl_xor(32)); O^T = mfma(V^T, P^T).
__global__ __launch_bounds__(256) void flash_kernel(
    const short* __restrict__ qb, const short* __restrict__ kb,
    const short* __restrict__ vt, short* __restrict__ ao)
{
  const int qt = 15 - blockIdx.x;  // heavy blocks first (causal imbalance)
  const int h = blockIdx.y, b = blockIdx.z;
  const int hkv = h >> 2;
  const int tid = threadIdx.x, w = tid >> 6, lane = tid & 63;
  const int l31 = lane & 31, hi = lane >> 5;
  const int hi16 = hi * 16;
  const int q0 = qt * 128 + w * 32;
  const int q_abs = q0 + l31;

  const short* Q  = qb + (long)(b * 32 + h) * 2048 * 128;
  const char*  Kg = (const char*)(kb + (long)(b * 8 + hkv) * 2048 * 128);
  const char*  Vg = (const char*)(vt + (long)(b * 8 + hkv) * 2048 * 128);  // [d][s]

  __shared__ short Ks[2][64 * 128];  // [kv][d], 16B chunks XOR-swizzled by kv&7
  __shared__ short Vs[2][128 * 64];  // [d][kv], 16B chunks XOR-swizzled by d&7

  int skX[4], svRow[4], svCol[4], Xo[4];
  #pragma unroll
  for (int i2 = 0; i2 < 4; ++i2) {
    int X = tid * 16 + i2 * 4096;
    Xo[i2] = X;
    skX[i2] = X ^ (((X >> 8) & 7) << 4);
    int sv = X ^ (((X >> 7) & 7) << 4);
    svRow[i2] = sv >> 7;
    svCol[i2] = sv & 127;
  }

  bf16x8 qf[8];
  #pragma unroll
  for (int c = 0; c < 8; ++c)
    qf[c] = *(const bf16x8*)&Q[(long)q_abs * 128 + c * 16 + hi * 8];

  f32x16 o[4];
  #pragma unroll
  for (int db = 0; db < 4; ++db)
    #pragma unroll
    for (int r = 0; r < 16; ++r) o[db][r] = 0.f;
  float m_ = -3e38f, l_ = 0.f;

  const float scale2 = 0.08838834764831845f * 1.4426950408889634f;
  const int nt = 2 * (qt + 1);
  const int ksw = (l31 & 7) << 4;

  #pragma unroll
  for (int i2 = 0; i2 < 4; ++i2) {
    gload16(Kg + skX[i2], (char*)Ks[0] + Xo[i2]);
    gload16(Vg + ((long)svRow[i2] * 4096 + svCol[i2]), (char*)Vs[0] + Xo[i2]);
  }

  for (int t = 0; t < nt; ++t) {
    const int kv0 = t * 64;
    const int cur = t & 1;
    __syncthreads();
    if (t + 1 < nt) {
      const long kvb = (long)(kv0 + 64);
      #pragma unroll
      for (int i2 = 0; i2 < 4; ++i2) {
        gload16(Kg + kvb * 256 + skX[i2], (char*)Ks[cur ^ 1] + Xo[i2]);
        gload16(Vg + ((long)svRow[i2] * 4096 + kvb * 2 + svCol[i2]),
                (char*)Vs[cur ^ 1] + Xo[i2]);
      }
    }
    if (kv0 > q0 + 31) continue;

    f32x16 s0, s1;
    #pragma unroll
    for (int r = 0; r < 16; ++r) { s0[r] = 0.f; s1[r] = 0.f; }
    const char* kbase = (const char*)Ks[cur] + l31 * 256;
    __builtin_amdgcn_s_setprio(1);
    #pragma unroll
    for (int c = 0; c < 8; ++c) {
      bf16x8 kf0 = *(const bf16x8*)(kbase + ((c * 32 + hi16) ^ ksw));
      bf16x8 kf1 = *(const bf16x8*)(kbase + 8192 + ((c * 32 + hi16) ^ ksw));
      s0 = __builtin_amdgcn_mfma_f32_32x32x16_bf16(kf0, qf[c], s0, 0, 0, 0);
      s1 = __builtin_amdgcn_mfma_f32_32x32x16_bf16(kf1, qf[c], s1, 0, 0, 0);
    }
    __builtin_amdgcn_s_setprio(0);

    const bool diag = (kv0 + 63 > q0);
    if (diag) {
      #pragma unroll
      for (int r = 0; r < 16; ++r) {
        int krow = (r & 3) + 8 * (r >> 2) + 4 * hi;
        if (kv0 + krow > q_abs)      s0[r] = -3e38f;
        if (kv0 + 32 + krow > q_abs) s1[r] = -3e38f;
      }
    }
    float mx = fmaxf(s0[0], s1[0]);
    #pragma unroll
    for (int r = 1; r < 16; ++r) mx = fmaxf(mx, fmaxf(s0[r], s1[r]));
    mx *= scale2;
    mx = fmaxf(mx, __shfl_xor(mx, 32));
    int need = mx > m_ + 11.5f;
    if (__any(need)) {
      float mn = fmaxf(m_, mx);
      float fac = exp2f(m_ - mn);
      m_ = mn;
      l_ *= fac;
      #pragma unroll
      for (int db = 0; db < 4; ++db)
        #pragma unroll
        for (int r = 0; r < 16; ++r) o[db][r] *= fac;
    }
    float rs = 0.f;
    #pragma unroll
    for (int r = 0; r < 16; ++r) {
      float p0 = exp2f(fmaf(s0[r], scale2, -m_));
      float p1 = exp2f(fmaf(s1[r], scale2, -m_));
      s0[r] = p0; s1[r] = p1;
      rs += p0 + p1;
    }
    rs += __shfl_xor(rs, 32);
    l_ += rs;

    const char* vbase = (const char*)Vs[cur] + l31 * 128;
    #pragma unroll
    for (int t2 = 0; t2 < 2; ++t2) {
      const f32x16 sp = t2 ? s1 : s0;
      unsigned wd[8];
      #pragma unroll
      for (int j = 0; j < 8; ++j) wd[j] = cvtpk(sp[2 * j], sp[2 * j + 1]);
      unsigned u0 = hi ? wd[0] : wd[2];
      unsigned u1 = hi ? wd[1] : wd[3];
      unsigned u2 = hi ? wd[4] : wd[6];
      unsigned u3 = hi ? wd[5] : wd[7];
      unsigned x0 = (unsigned)__shfl_xor((int)u0, 32);
      unsigned x1 = (unsigned)__shfl_xor((int)u1, 32);
      unsigned x2 = (unsigned)__shfl_xor((int)u2, 32);
      unsigned x3 = (unsigned)__shfl_xor((int)u3, 32);
      BW f0, f1;
      f0.u[0] = hi ? x0 : wd[0];
      f0.u[1] = hi ? x1 : wd[1];
      f0.u[2] = hi ? wd[2] : x0;
      f0.u[3] = hi ? wd[3] : x1;
      f1.u[0] = hi ? x2 : wd[4];
      f1.u[1] = hi ? x3 : wd[5];
      f1.u[2] = hi ? wd[6] : x2;
      f1.u[3] = hi ? wd[7] : x3;
      __builtin_amdgcn_s_setprio(1);
      #pragma unroll
      for (int cc = 0; cc < 2; ++cc) {
        const BW& fr = cc ? f1 : f0;
        #pragma unroll
        for (int db = 0; db < 4; ++db) {
          bf16x8 vf = *(const bf16x8*)(vbase + db * 4096 +
                                       ((t2 * 64 + cc * 32 + hi16) ^ ksw));
          o[db] = __builtin_amdgcn_mfma_f32_32x32x16_bf16(vf, fr.v, o[db], 0, 0, 0);
        }
      }
      __builtin_amdgcn_s_setprio(0);
    }
  }

  float invl = 1.0f / l_;
  const long aorow = ((long)(b * 2048 + q_abs)) * 4096 + h * 128 + hi * 4;
  #pragma unroll
  for (int db = 0; db < 4; ++db)
    #pragma unroll
    for (int r = 0; r < 16; ++r) {
      int doff = db * 32 + (r & 3) + 8 * (r >> 2);
      ao[aorow + doff] = f2bf(o[db][r] * invl);
    }
}

// ---------------- launcher --------------------------------------------------
extern "C" void kernel_launch(void* const* d_in, const int* in_sizes, int n_in,
                              void* d_out, int out_size, void* d_ws, size_t ws_size,
                              hipStream_t stream) {
  const float* x  = (const float*)d_in[0];
  const float* wq = (const float*)d_in[1];
  const float* wk = (const float*)d_in[2];
  const float* wv = (const float*)d_in[3];
  const float* wo = (const float*)d_in[4];
  float* out = (float*)d_out;

  char* ws = (char*)d_ws;
  short* xb    = (short*)(ws);               // x bf16; later reused as attn_out
  short* wqkvb = (short*)(ws + 33554432);    // wq|wk|wv bf16 (6144x4096)
  short* wob   = (short*)(ws + 83886080);
  short* qb    = (short*)(ws + 117440512);   // (B,H,S,D)
  short* kb    = (short*)(ws + 150994944);   // (B,Hkv,S,D)
  short* vb    = (short*)(ws + 159383552);   // (B,Hkv,D,S)  TRANSPOSED
  short* ao    = xb;

  float* nk = out + 16777216;  // new_k fp32 (B,Hkv,S,D)
  float* nv = out + 20971520;  // new_v fp32

  cast8_kernel<<<8192, 256, 0, stream>>>(x,  xb,    16777216);
  cast8_kernel<<<8192, 256, 0, stream>>>(wq, wqkvb, 16777216);
  cast8_kernel<<<2048, 256, 0, stream>>>(wk, wqkvb + 16777216, 4194304);
  cast8_kernel<<<2048, 256, 0, stream>>>(wv, wqkvb + 20971520, 4194304);
  cast8_kernel<<<8192, 256, 0, stream>>>(wo, wob,   16777216);

  gemm256<1><<<dim3(24, 16), 512, 0, stream>>>(xb, wqkvb, nullptr, qb, kb, vb, nk, nv);
  rope_kernel<<<10240, 256, 0, stream>>>(qb, kb);
  flash_kernel<<<dim3(16, 32, 2), 256, 0, stream>>>(qb, kb, vb, ao);
  gemm256<0><<<dim3(16, 16), 512, 0, stream>>>(ao, wob, out, nullptr, nullptr, nullptr,
                                               nullptr, nullptr);
}

// Round 6
// 636.825 us; speedup vs baseline: 1.9681x; 1.2458x over previous
//
#include <hip/hip_runtime.h>
#include <hip/hip_bf16.h>

typedef __attribute__((ext_vector_type(8)))  short   s16x8;
typedef __attribute__((ext_vector_type(8)))  __bf16  bf16x8;
typedef __attribute__((ext_vector_type(4)))  float   f32x4;
typedef __attribute__((ext_vector_type(16))) float   f32x16;

#define DEV static __device__ __forceinline__

DEV short f2bf(float f) {
  unsigned u = __builtin_bit_cast(unsigned, f);
  u = (u + 0x7fff + ((u >> 16) & 1)) >> 16;
  return (short)u;
}
DEV float bf2f(short s) {
  unsigned u = ((unsigned)(unsigned short)s) << 16;
  return __builtin_bit_cast(float, u);
}

DEV void gload16(const void* g, void* l) {
  __builtin_amdgcn_global_load_lds(
      (const __attribute__((address_space(1))) unsigned int*)g,
      (__attribute__((address_space(3))) unsigned int*)l, 16, 0, 0);
}

DEV unsigned cvtpk(float lo, float hi) {
  unsigned r;
  asm("v_cvt_pk_bf16_f32 %0, %1, %2" : "=v"(r) : "v"(lo), "v"(hi));
  return r;
}

typedef union { unsigned u[4]; bf16x8 v; } BW;

// ---------------- fused cast fp32 -> bf16 for all 5 inputs ------------------
// regions (in 8-elem vectors): x 2097152 | wq 2097152 | wk 524288 | wv 524288
// | wo 2097152.  One launch instead of five.
__global__ __launch_bounds__(256) void cast_all(
    const float* __restrict__ x,  const float* __restrict__ wq,
    const float* __restrict__ wk, const float* __restrict__ wv,
    const float* __restrict__ wo,
    short* __restrict__ xb, short* __restrict__ wqkvb, short* __restrict__ wob) {
  long i = (long)blockIdx.x * 256 + threadIdx.x;  // vector index
  const float* src;
  short* dst;
  long off;
  if (i < 2097152)       { src = x;  dst = xb;               off = i; }
  else if (i < 4194304)  { src = wq; dst = wqkvb;            off = i - 2097152; }
  else if (i < 4718592)  { src = wk; dst = wqkvb + 16777216; off = i - 4194304; }
  else if (i < 5242880)  { src = wv; dst = wqkvb + 20971520; off = i - 4718592; }
  else                   { src = wo; dst = wob;              off = i - 5242880; }
  long e = off * 8;
  float4 a = *(const float4*)(src + e);
  float4 b = *(const float4*)(src + e + 4);
  s16x8 o;
  o[0] = f2bf(a.x); o[1] = f2bf(a.y); o[2] = f2bf(a.z); o[3] = f2bf(a.w);
  o[4] = f2bf(b.x); o[5] = f2bf(b.y); o[6] = f2bf(b.z); o[7] = f2bf(b.w);
  *(s16x8*)(dst + e) = o;
}

// ---------------- GEMM 256x256, 8 waves, BK=64, deep-pipelined --------------
// C[M][N] = A[M][K] @ W[N][K]^T, bf16 in, fp32 acc. K=4096 fixed.
// LDS: 2 buffers x (A 256x64 + B 256x64), XOR-swizzled ((row&7)<<4) via
// pre-swizzled global source (rule #21). Counted vmcnt(8) at tile boundary
// (never drains to 0 mid-loop). Raw s_barrier only. T1 XCD swizzle on grid.
// MODE 0: fp32 C write (N=4096). MODE 1: qkv split epilogue (N=6144).
template<int MODE>
__global__ __launch_bounds__(512, 2) void gemm256(
    const short* __restrict__ A, const short* __restrict__ W,
    float* __restrict__ Cout,
    short* __restrict__ qb, short* __restrict__ kb, short* __restrict__ vb,
    float* __restrict__ nk, float* __restrict__ nv)
{
  const int K = 4096;
  __shared__ short lds[2][2][256 * 64];  // [buf][0=A,1=B]

  const int tid = threadIdx.x;
  const int lane = tid & 63;
  const int w = tid >> 6;
  const int wm = w >> 2, wn = w & 3;          // 2 x 4 waves
  const int l15 = lane & 15, lg = lane >> 4;
  const int swz = (l15 & 7) << 4;

  // T1: bijective XCD swizzle (grid size divisible by 8 in both launches)
  const int NTN = gridDim.x;
  int nwg = gridDim.x * gridDim.y;
  int orig = blockIdx.y * gridDim.x + blockIdx.x;
  int cpx = nwg >> 3;
  int snew = (orig & 7) * cpx + (orig >> 3);
  const int tn = snew % NTN, tm = snew / NTN;

  const char* Ac = (const char*)A;
  const char* Wc = (const char*)W;

  // per-thread staging: dest X linear, source col pre-swizzled
  int Xl[4];
  long abase[4], bbase[4];
  #pragma unroll
  for (int l4 = 0; l4 < 4; ++l4) {
    int X = tid * 16 + l4 * 8192;
    int row = X >> 7;
    int colS = (X & 127) ^ (((X >> 7) & 7) << 4);
    Xl[l4] = X;
    abase[l4] = (long)(tm * 256 + row) * 8192 + colS;
    bbase[l4] = (long)(tn * 256 + row) * 8192 + colS;
  }

#define STAGE(tt, bb)                                                       \
  {                                                                         \
    const long kof_ = (long)(tt) * 128;                                     \
    _Pragma("unroll")                                                       \
    for (int l4 = 0; l4 < 4; ++l4)                                          \
      gload16(Ac + abase[l4] + kof_, (char*)&lds[bb][0][0] + Xl[l4]);       \
    _Pragma("unroll")                                                       \
    for (int l4 = 0; l4 < 4; ++l4)                                          \
      gload16(Wc + bbase[l4] + kof_, (char*)&lds[bb][1][0] + Xl[l4]);       \
  }

  f32x4 zero = {0.f, 0.f, 0.f, 0.f};
  f32x4 acc[8][4];
  #pragma unroll
  for (int i = 0; i < 8; ++i)
    #pragma unroll
    for (int j = 0; j < 4; ++j) acc[i][j] = zero;

  // fragment read offsets (row&7 == l15&7, invariant)
  const int aro = (wm * 128 + l15) * 128;          // byte row base (A)
  const int bro = (wn * 64 + l15) * 128;           // byte row base (B)
  const int cs0 = ((0 << 6) | (lg << 4)) ^ swz;    // khalf 0 col bytes
  const int cs1 = ((1 << 6) | (lg << 4)) ^ swz;    // khalf 1 col bytes

  // prologue: stage tiles 0,1; wait tile 0
  STAGE(0, 0)
  STAGE(1, 1)
  asm volatile("s_waitcnt vmcnt(8)" ::: "memory");
  __builtin_amdgcn_s_barrier();

  for (int t = 0; t < 64; ++t) {
    const int bt = t & 1;
    const char* LA = (const char*)&lds[bt][0][0];
    const char* LB = (const char*)&lds[bt][1][0];

    // phase 0 reads all B-frags + A-frags mr0,1
    bf16x8 bfr[4][2];
    #pragma unroll
    for (int nr = 0; nr < 4; ++nr) {
      bfr[nr][0] = *(const bf16x8*)(LB + bro + nr * 2048 + cs0);
      bfr[nr][1] = *(const bf16x8*)(LB + bro + nr * 2048 + cs1);
    }
    #pragma unroll
    for (int p = 0; p < 4; ++p) {
      bf16x8 af[2][2];
      #pragma unroll
      for (int mi = 0; mi < 2; ++mi) {
        af[mi][0] = *(const bf16x8*)(LA + aro + (2 * p + mi) * 2048 + cs0);
        af[mi][1] = *(const bf16x8*)(LA + aro + (2 * p + mi) * 2048 + cs1);
      }
      __builtin_amdgcn_s_barrier();
      asm volatile("s_waitcnt lgkmcnt(0)" ::: "memory");
      __builtin_amdgcn_sched_barrier(0);
      __builtin_amdgcn_s_setprio(1);
      #pragma unroll
      for (int mi = 0; mi < 2; ++mi)
        #pragma unroll
        for (int nr = 0; nr < 4; ++nr) {
          acc[2 * p + mi][nr] = __builtin_amdgcn_mfma_f32_16x16x32_bf16(
              af[mi][0], bfr[nr][0], acc[2 * p + mi][nr], 0, 0, 0);
          acc[2 * p + mi][nr] = __builtin_amdgcn_mfma_f32_16x16x32_bf16(
              af[mi][1], bfr[nr][1], acc[2 * p + mi][nr], 0, 0, 0);
        }
      __builtin_amdgcn_s_setprio(0);
      __builtin_amdgcn_s_barrier();
    }
    // boundary: all reads of buf bt done (phase-3 barrier) -> refill it
    if (t < 62) {
      STAGE(t + 2, bt)
      asm volatile("s_waitcnt vmcnt(8)" ::: "memory");  // tile t+1 landed
      __builtin_amdgcn_s_barrier();
    } else if (t == 62) {
      asm volatile("s_waitcnt vmcnt(0)" ::: "memory");  // tile 63 landed
      __builtin_amdgcn_s_barrier();
    }
  }
#undef STAGE

  // epilogue
  #pragma unroll
  for (int mr = 0; mr < 8; ++mr) {
    int mbase = tm * 256 + wm * 128 + mr * 16 + lg * 4;
    #pragma unroll
    for (int nr = 0; nr < 4; ++nr) {
      int col = tn * 256 + wn * 64 + nr * 16 + l15;
      #pragma unroll
      for (int r = 0; r < 4; ++r) {
        int m = mbase + r;
        float v = acc[mr][nr][r];
        if (MODE == 0) {
          Cout[(long)m * 4096 + col] = v;
        } else {
          int b = m >> 11, s = m & 2047;
          if (col < 4096) {
            int h = col >> 7, d = col & 127;
            qb[((long)((b * 32 + h) * 2048 + s)) * 128 + d] = f2bf(v);
          } else if (col < 5120) {
            int c2 = col - 4096;
            int h = c2 >> 7, d = c2 & 127;
            long o = ((long)((b * 8 + h) * 2048 + s)) * 128 + d;
            kb[o] = f2bf(v);
            nk[o] = v;
          } else {
            int c2 = col - 5120;
            int h = c2 >> 7, d = c2 & 127;
            long o = ((long)((b * 8 + h) * 2048 + s)) * 128 + d;
            nv[o] = v;
            vb[((long)((b * 8 + h) * 128 + d)) * 2048 + s] = f2bf(v);  // [b][hkv][d][s]
          }
        }
      }
    }
  }
}

// ---------------- RoPE in-place on q and k (bf16, interleaved pairs) --------
__global__ __launch_bounds__(256) void rope_kernel(short* __restrict__ qb,
                                                   short* __restrict__ kb) {
  const long QV = 2097152;
  const long TV = 2621440;
  long i = (long)blockIdx.x * 256 + threadIdx.x;
  if (i >= TV) return;
  short* p;
  long e;
  if (i < QV) { e = i * 8; p = qb + e; }
  else        { e = (i - QV) * 8; p = kb + e; }
  int d0 = (int)(e & 127);
  int s  = (int)((e >> 7) & 2047);
  int jb = d0 >> 1;
  s16x8 v = *(const s16x8*)p;
  #pragma unroll
  for (int t = 0; t < 4; ++t) {
    float x1 = bf2f(v[2 * t]), x2 = bf2f(v[2 * t + 1]);
    int j = jb + t;
    float inv = __expf(-0.14391157f * (float)j);  // 10000^(-2j/128)
    float ang = (float)s * inv;
    float sn, cs;
    __sincosf(ang, &sn, &cs);
    v[2 * t]     = f2bf(x1 * cs - x2 * sn);
    v[2 * t + 1] = f2bf(x1 * sn + x2 * cs);
  }
  *(s16x8*)p = v;
}

// ---------------- Flash attention v5: LPT dispatch, swapped-QK --------------
// grid (1024) 1-D; bid>>6 selects qt HEAVIEST-FIRST (all qt=15 blocks first),
// bid&63 selects (h,b). 256 thr = 4 waves; Q tile 128, wave = 32 q, KV = 64.
// 32x32x16 MFMA. S^T = mfma(K,Q): lane owns q = lane&31 (m_, l_ scalar/lane).
// P packed to bf16 in-register (cvt_pk + shfl_xor(32)); O^T = mfma(V^T, P^T).
__global__ __launch_bounds__(256) void flash_kernel(
    const short* __restrict__ qb, const short* __restrict__ kb,
    const short* __restrict__ vt, short* __restrict__ ao)
{
  const int bid = blockIdx.x;
  const int qt = 15 - (bid >> 6);   // true LPT: heaviest blocks dispatch first
  const int hb = bid & 63;
  const int h = hb & 31, b = hb >> 5;
  const int hkv = h >> 2;
  const int tid = threadIdx.x, w = tid >> 6, lane = tid & 63;
  const int l31 = lane & 31, hi = lane >> 5;
  const int hi16 = hi * 16;
  const int q0 = qt * 128 + w * 32;
  const int q_abs = q0 + l31;

  const short* Q  = qb + (long)(b * 32 + h) * 2048 * 128;
  const char*  Kg = (const char*)(kb + (long)(b * 8 + hkv) * 2048 * 128);
  const char*  Vg = (const char*)(vt + (long)(b * 8 + hkv) * 2048 * 128);  // [d][s]

  __shared__ short Ks[2][64 * 128];  // [kv][d], 16B chunks XOR-swizzled by kv&7
  __shared__ short Vs[2][128 * 64];  // [d][kv], 16B chunks XOR-swizzled by d&7

  int skX[4], svRow[4], svCol[4], Xo[4];
  #pragma unroll
  for (int i2 = 0; i2 < 4; ++i2) {
    int X = tid * 16 + i2 * 4096;
    Xo[i2] = X;
    skX[i2] = X ^ (((X >> 8) & 7) << 4);
    int sv = X ^ (((X >> 7) & 7) << 4);
    svRow[i2] = sv >> 7;
    svCol[i2] = sv & 127;
  }

  bf16x8 qf[8];
  #pragma unroll
  for (int c = 0; c < 8; ++c)
    qf[c] = *(const bf16x8*)&Q[(long)q_abs * 128 + c * 16 + hi * 8];

  f32x16 o[4];
  #pragma unroll
  for (int db = 0; db < 4; ++db)
    #pragma unroll
    for (int r = 0; r < 16; ++r) o[db][r] = 0.f;
  float m_ = -3e38f, l_ = 0.f;

  const float scale2 = 0.08838834764831845f * 1.4426950408889634f;
  const int nt = 2 * (qt + 1);
  const int ksw = (l31 & 7) << 4;

  #pragma unroll
  for (int i2 = 0; i2 < 4; ++i2) {
    gload16(Kg + skX[i2], (char*)Ks[0] + Xo[i2]);
    gload16(Vg + ((long)svRow[i2] * 4096 + svCol[i2]), (char*)Vs[0] + Xo[i2]);
  }

  for (int t = 0; t < nt; ++t) {
    const int kv0 = t * 64;
    const int cur = t & 1;
    __syncthreads();
    if (t + 1 < nt) {
      const long kvb = (long)(kv0 + 64);
      #pragma unroll
      for (int i2 = 0; i2 < 4; ++i2) {
        gload16(Kg + kvb * 256 + skX[i2], (char*)Ks[cur ^ 1] + Xo[i2]);
        gload16(Vg + ((long)svRow[i2] * 4096 + kvb * 2 + svCol[i2]),
                (char*)Vs[cur ^ 1] + Xo[i2]);
      }
    }
    if (kv0 > q0 + 31) continue;

    f32x16 s0, s1;
    #pragma unroll
    for (int r = 0; r < 16; ++r) { s0[r] = 0.f; s1[r] = 0.f; }
    const char* kbase = (const char*)Ks[cur] + l31 * 256;
    __builtin_amdgcn_s_setprio(1);
    #pragma unroll
    for (int c = 0; c < 8; ++c) {
      bf16x8 kf0 = *(const bf16x8*)(kbase + ((c * 32 + hi16) ^ ksw));
      bf16x8 kf1 = *(const bf16x8*)(kbase + 8192 + ((c * 32 + hi16) ^ ksw));
      s0 = __builtin_amdgcn_mfma_f32_32x32x16_bf16(kf0, qf[c], s0, 0, 0, 0);
      s1 = __builtin_amdgcn_mfma_f32_32x32x16_bf16(kf1, qf[c], s1, 0, 0, 0);
    }
    __builtin_amdgcn_s_setprio(0);

    const bool diag = (kv0 + 63 > q0);
    if (diag) {
      #pragma unroll
      for (int r = 0; r < 16; ++r) {
        int krow = (r & 3) + 8 * (r >> 2) + 4 * hi;
        if (kv0 + krow > q_abs)      s0[r] = -3e38f;
        if (kv0 + 32 + krow > q_abs) s1[r] = -3e38f;
      }
    }
    float mx = fmaxf(s0[0], s1[0]);
    #pragma unroll
    for (int r = 1; r < 16; ++r) mx = fmaxf(mx, fmaxf(s0[r], s1[r]));
    mx *= scale2;
    mx = fmaxf(mx, __shfl_xor(mx, 32));
    int need = mx > m_ + 11.5f;
    if (__any(need)) {
      float mn = fmaxf(m_, mx);
      float fac = exp2f(m_ - mn);
      m_ = mn;
      l_ *= fac;
      #pragma unroll
      for (int db = 0; db < 4; ++db)
        #pragma unroll
        for (int r = 0; r < 16; ++r) o[db][r] *= fac;
    }
    float rs = 0.f;
    #pragma unroll
    for (int r = 0; r < 16; ++r) {
      float p0 = exp2f(fmaf(s0[r], scale2, -m_));
      float p1 = exp2f(fmaf(s1[r], scale2, -m_));
      s0[r] = p0; s1[r] = p1;
      rs += p0 + p1;
    }
    rs += __shfl_xor(rs, 32);
    l_ += rs;

    const char* vbase = (const char*)Vs[cur] + l31 * 128;
    #pragma unroll
    for (int t2 = 0; t2 < 2; ++t2) {
      const f32x16 sp = t2 ? s1 : s0;
      unsigned wd[8];
      #pragma unroll
      for (int j = 0; j < 8; ++j) wd[j] = cvtpk(sp[2 * j], sp[2 * j + 1]);
      unsigned u0 = hi ? wd[0] : wd[2];
      unsigned u1 = hi ? wd[1] : wd[3];
      unsigned u2 = hi ? wd[4] : wd[6];
      unsigned u3 = hi ? wd[5] : wd[7];
      unsigned x0 = (unsigned)__shfl_xor((int)u0, 32);
      unsigned x1 = (unsigned)__shfl_xor((int)u1, 32);
      unsigned x2 = (unsigned)__shfl_xor((int)u2, 32);
      unsigned x3 = (unsigned)__shfl_xor((int)u3, 32);
      BW f0, f1;
      f0.u[0] = hi ? x0 : wd[0];
      f0.u[1] = hi ? x1 : wd[1];
      f0.u[2] = hi ? wd[2] : x0;
      f0.u[3] = hi ? wd[3] : x1;
      f1.u[0] = hi ? x2 : wd[4];
      f1.u[1] = hi ? x3 : wd[5];
      f1.u[2] = hi ? wd[6] : x2;
      f1.u[3] = hi ? wd[7] : x3;
      __builtin_amdgcn_s_setprio(1);
      #pragma unroll
      for (int cc = 0; cc < 2; ++cc) {
        const BW& fr = cc ? f1 : f0;
        #pragma unroll
        for (int db = 0; db < 4; ++db) {
          bf16x8 vf = *(const bf16x8*)(vbase + db * 4096 +
                                       ((t2 * 64 + cc * 32 + hi16) ^ ksw));
          o[db] = __builtin_amdgcn_mfma_f32_32x32x16_bf16(vf, fr.v, o[db], 0, 0, 0);
        }
      }
      __builtin_amdgcn_s_setprio(0);
    }
  }

  float invl = 1.0f / l_;
  const long aorow = ((long)(b * 2048 + q_abs)) * 4096 + h * 128 + hi * 4;
  #pragma unroll
  for (int db = 0; db < 4; ++db)
    #pragma unroll
    for (int r = 0; r < 16; ++r) {
      int doff = db * 32 + (r & 3) + 8 * (r >> 2);
      ao[aorow + doff] = f2bf(o[db][r] * invl);
    }
}

// ---------------- launcher --------------------------------------------------
extern "C" void kernel_launch(void* const* d_in, const int* in_sizes, int n_in,
                              void* d_out, int out_size, void* d_ws, size_t ws_size,
                              hipStream_t stream) {
  const float* x  = (const float*)d_in[0];
  const float* wq = (const float*)d_in[1];
  const float* wk = (const float*)d_in[2];
  const float* wv = (const float*)d_in[3];
  const float* wo = (const float*)d_in[4];
  float* out = (float*)d_out;

  char* ws = (char*)d_ws;
  short* xb    = (short*)(ws);               // x bf16; later reused as attn_out
  short* wqkvb = (short*)(ws + 33554432);    // wq|wk|wv bf16 (6144x4096)
  short* wob   = (short*)(ws + 83886080);
  short* qb    = (short*)(ws + 117440512);   // (B,H,S,D)
  short* kb    = (short*)(ws + 150994944);   // (B,Hkv,S,D)
  short* vb    = (short*)(ws + 159383552);   // (B,Hkv,D,S)  TRANSPOSED
  short* ao    = xb;

  float* nk = out + 16777216;  // new_k fp32 (B,Hkv,S,D)
  float* nv = out + 20971520;  // new_v fp32

  cast_all<<<28672, 256, 0, stream>>>(x, wq, wk, wv, wo, xb, wqkvb, wob);

  gemm256<1><<<dim3(24, 16), 512, 0, stream>>>(xb, wqkvb, nullptr, qb, kb, vb, nk, nv);
  rope_kernel<<<10240, 256, 0, stream>>>(qb, kb);
  flash_kernel<<<1024, 256, 0, stream>>>(qb, kb, vb, ao);
  gemm256<0><<<dim3(16, 16), 512, 0, stream>>>(ao, wob, out, nullptr, nullptr, nullptr,
                                               nullptr, nullptr);
}

// Round 7
// 599.453 us; speedup vs baseline: 2.0908x; 1.0623x over previous
//
#include <hip/hip_runtime.h>
#include <hip/hip_bf16.h>

typedef __attribute__((ext_vector_type(8)))  short   s16x8;
typedef __attribute__((ext_vector_type(8)))  __bf16  bf16x8;
typedef __attribute__((ext_vector_type(4)))  float   f32x4;
typedef __attribute__((ext_vector_type(16))) float   f32x16;

#define DEV static __device__ __forceinline__

DEV short f2bf(float f) {
  unsigned u = __builtin_bit_cast(unsigned, f);
  u = (u + 0x7fff + ((u >> 16) & 1)) >> 16;
  return (short)u;
}
DEV float bf2f(short s) {
  unsigned u = ((unsigned)(unsigned short)s) << 16;
  return __builtin_bit_cast(float, u);
}

DEV void gload16(const void* g, void* l) {
  __builtin_amdgcn_global_load_lds(
      (const __attribute__((address_space(1))) unsigned int*)g,
      (__attribute__((address_space(3))) unsigned int*)l, 16, 0, 0);
}

DEV unsigned cvtpk(float lo, float hi) {
  unsigned r;
  asm("v_cvt_pk_bf16_f32 %0, %1, %2" : "=v"(r) : "v"(lo), "v"(hi));
  return r;
}

typedef union { unsigned u[4]; bf16x8 v; } BW;

// ---------------- fused cast fp32 -> bf16 for all 5 inputs ------------------
__global__ __launch_bounds__(256) void cast_all(
    const float* __restrict__ x,  const float* __restrict__ wq,
    const float* __restrict__ wk, const float* __restrict__ wv,
    const float* __restrict__ wo,
    short* __restrict__ xb, short* __restrict__ wqkvb, short* __restrict__ wob) {
  long i = (long)blockIdx.x * 256 + threadIdx.x;  // vector index
  const float* src;
  short* dst;
  long off;
  if (i < 2097152)       { src = x;  dst = xb;               off = i; }
  else if (i < 4194304)  { src = wq; dst = wqkvb;            off = i - 2097152; }
  else if (i < 4718592)  { src = wk; dst = wqkvb + 16777216; off = i - 4194304; }
  else if (i < 5242880)  { src = wv; dst = wqkvb + 20971520; off = i - 4718592; }
  else                   { src = wo; dst = wob;              off = i - 5242880; }
  long e = off * 8;
  float4 a = *(const float4*)(src + e);
  float4 b = *(const float4*)(src + e + 4);
  s16x8 o;
  o[0] = f2bf(a.x); o[1] = f2bf(a.y); o[2] = f2bf(a.z); o[3] = f2bf(a.w);
  o[4] = f2bf(b.x); o[5] = f2bf(b.y); o[6] = f2bf(b.z); o[7] = f2bf(b.w);
  *(s16x8*)(dst + e) = o;
}

// ---------------- GEMM 256x256, 8 waves, BK=64, 2-barrier pipelined ---------
// C[M][N] = A[M][K] @ W[N][K]^T, bf16 in, fp32 acc. K=4096 fixed.
// Per K-tile: read B-frags + A0; 4 MFMA phases pipelined on counted
// lgkmcnt(4)+sched_barrier (rule #18), named ping-pong A regs (rule #20);
// ONE barrier before STAGE(t+2) (all reads of buf done), vmcnt(8) AFTER the
// last MFMA cluster, ONE barrier after. 1-D grid; XCD supertile mapping:
// XCD c = bid&7 owns an 8tm x RTN tn rectangle (L2 working set ~28MB).
// MODE 0: fp32 C write (N=4096, 256 blocks). MODE 1: qkv epilogue (384).
template<int MODE>
__global__ __launch_bounds__(512, 2) void gemm256(
    const short* __restrict__ A, const short* __restrict__ W,
    float* __restrict__ Cout,
    short* __restrict__ qb, short* __restrict__ kb, short* __restrict__ vb,
    float* __restrict__ nk, float* __restrict__ nv)
{
  __shared__ short lds[2][2][256 * 64];  // [buf][0=A,1=B]

  const int tid = threadIdx.x;
  const int lane = tid & 63;
  const int w = tid >> 6;
  const int wm = w >> 2, wn = w & 3;          // 2 x 4 waves
  const int l15 = lane & 15, lg = lane >> 4;
  const int swz = (l15 & 7) << 4;

  // XCD supertile: c = bid&7 -> rect (c>>2)*8 rows x (c&3)*RTN cols
  const int RTN = MODE ? 6 : 4;               // 24 or 16 tn tiles / 4 XCD cols
  int c = blockIdx.x & 7, j = blockIdx.x >> 3;
  const int tm = (c >> 2) * 8 + (j & 7);
  const int tn = (c & 3) * RTN + (j >> 3);

  const char* Ac = (const char*)A;
  const char* Wc = (const char*)W;

  // per-thread staging: dest X linear, source col pre-swizzled (rule #21)
  int Xl[4];
  long abase[4], bbase[4];
  #pragma unroll
  for (int l4 = 0; l4 < 4; ++l4) {
    int X = tid * 16 + l4 * 8192;
    int row = X >> 7;
    int colS = (X & 127) ^ (((X >> 7) & 7) << 4);
    Xl[l4] = X;
    abase[l4] = (long)(tm * 256 + row) * 8192 + colS;
    bbase[l4] = (long)(tn * 256 + row) * 8192 + colS;
  }

#define STAGE(tt, bb)                                                       \
  {                                                                         \
    const long kof_ = (long)(tt) * 128;                                     \
    _Pragma("unroll")                                                       \
    for (int l4 = 0; l4 < 4; ++l4)                                          \
      gload16(Ac + abase[l4] + kof_, (char*)&lds[bb][0][0] + Xl[l4]);       \
    _Pragma("unroll")                                                       \
    for (int l4 = 0; l4 < 4; ++l4)                                          \
      gload16(Wc + bbase[l4] + kof_, (char*)&lds[bb][1][0] + Xl[l4]);       \
  }

  f32x4 zero = {0.f, 0.f, 0.f, 0.f};
  f32x4 acc[8][4];
  #pragma unroll
  for (int i = 0; i < 8; ++i)
    #pragma unroll
    for (int jj = 0; jj < 4; ++jj) acc[i][jj] = zero;

  const int aro = (wm * 128 + l15) * 128;          // byte row base (A)
  const int bro = (wn * 64 + l15) * 128;           // byte row base (B)
  const int cs0 = ((lg << 4)) ^ swz;               // khalf 0 col bytes
  const int cs1 = ((1 << 6) | (lg << 4)) ^ swz;    // khalf 1 col bytes

// read one A phase (rows R0, R0+1) into named frags
#define RDA(a00, a01, a10, a11, R0)                                         \
  a00 = *(const bf16x8*)(LA + aro + (R0) * 2048 + cs0);                     \
  a01 = *(const bf16x8*)(LA + aro + (R0) * 2048 + cs1);                     \
  a10 = *(const bf16x8*)(LA + aro + (R0 + 1) * 2048 + cs0);                 \
  a11 = *(const bf16x8*)(LA + aro + (R0 + 1) * 2048 + cs1);

#define MFMAP(a00, a01, a10, a11, P)                                        \
  __builtin_amdgcn_s_setprio(1);                                            \
  _Pragma("unroll")                                                         \
  for (int nr = 0; nr < 4; ++nr) {                                          \
    acc[2 * (P)][nr] = __builtin_amdgcn_mfma_f32_16x16x32_bf16(             \
        a00, bfr[nr][0], acc[2 * (P)][nr], 0, 0, 0);                        \
    acc[2 * (P)][nr] = __builtin_amdgcn_mfma_f32_16x16x32_bf16(             \
        a01, bfr[nr][1], acc[2 * (P)][nr], 0, 0, 0);                        \
    acc[2 * (P) + 1][nr] = __builtin_amdgcn_mfma_f32_16x16x32_bf16(         \
        a10, bfr[nr][0], acc[2 * (P) + 1][nr], 0, 0, 0);                    \
    acc[2 * (P) + 1][nr] = __builtin_amdgcn_mfma_f32_16x16x32_bf16(         \
        a11, bfr[nr][1], acc[2 * (P) + 1][nr], 0, 0, 0);                    \
  }                                                                         \
  __builtin_amdgcn_s_setprio(0);

  // prologue: stage tiles 0,1; wait tile 0
  STAGE(0, 0)
  STAGE(1, 1)
  asm volatile("s_waitcnt vmcnt(8)" ::: "memory");
  __builtin_amdgcn_s_barrier();

  for (int t = 0; t < 64; ++t) {
    const int bt = t & 1;
    const char* LA = (const char*)&lds[bt][0][0];
    const char* LB = (const char*)&lds[bt][1][0];

    bf16x8 bfr[4][2];
    #pragma unroll
    for (int nr = 0; nr < 4; ++nr) {
      bfr[nr][0] = *(const bf16x8*)(LB + bro + nr * 2048 + cs0);
      bfr[nr][1] = *(const bf16x8*)(LB + bro + nr * 2048 + cs1);
    }
    bf16x8 pA00, pA01, pA10, pA11;   // ping
    bf16x8 pB00, pB01, pB10, pB11;   // pong
    RDA(pA00, pA01, pA10, pA11, 0)
    // phase 0
    RDA(pB00, pB01, pB10, pB11, 2)
    asm volatile("s_waitcnt lgkmcnt(4)" ::: "memory");
    __builtin_amdgcn_sched_barrier(0);
    MFMAP(pA00, pA01, pA10, pA11, 0)
    // phase 1
    RDA(pA00, pA01, pA10, pA11, 4)
    asm volatile("s_waitcnt lgkmcnt(4)" ::: "memory");
    __builtin_amdgcn_sched_barrier(0);
    MFMAP(pB00, pB01, pB10, pB11, 1)
    // phase 2
    RDA(pB00, pB01, pB10, pB11, 6)
    asm volatile("s_waitcnt lgkmcnt(4)" ::: "memory");
    __builtin_amdgcn_sched_barrier(0);
    MFMAP(pA00, pA01, pA10, pA11, 2)
    // phase 3: all LDS reads of buf bt done -> barrier -> refill bt
    asm volatile("s_waitcnt lgkmcnt(0)" ::: "memory");
    __builtin_amdgcn_sched_barrier(0);
    __builtin_amdgcn_s_barrier();
    if (t < 62) {
      STAGE(t + 2, bt)
    }
    MFMAP(pB00, pB01, pB10, pB11, 3)
    if (t < 62) {
      asm volatile("s_waitcnt vmcnt(8)" ::: "memory");  // tile t+1 landed
      __builtin_amdgcn_s_barrier();
    } else if (t == 62) {
      asm volatile("s_waitcnt vmcnt(0)" ::: "memory");  // tile 63 landed
      __builtin_amdgcn_s_barrier();
    }
  }
#undef STAGE
#undef RDA
#undef MFMAP

  // epilogue
  #pragma unroll
  for (int mr = 0; mr < 8; ++mr) {
    int mbase = tm * 256 + wm * 128 + mr * 16 + lg * 4;
    #pragma unroll
    for (int nr = 0; nr < 4; ++nr) {
      int col = tn * 256 + wn * 64 + nr * 16 + l15;
      #pragma unroll
      for (int r = 0; r < 4; ++r) {
        int m = mbase + r;
        float v = acc[mr][nr][r];
        if (MODE == 0) {
          Cout[(long)m * 4096 + col] = v;
        } else {
          int b = m >> 11, s = m & 2047;
          if (col < 4096) {
            int h = col >> 7, d = col & 127;
            qb[((long)((b * 32 + h) * 2048 + s)) * 128 + d] = f2bf(v);
          } else if (col < 5120) {
            int c2 = col - 4096;
            int h = c2 >> 7, d = c2 & 127;
            long o = ((long)((b * 8 + h) * 2048 + s)) * 128 + d;
            kb[o] = f2bf(v);
            nk[o] = v;
          } else {
            int c2 = col - 5120;
            int h = c2 >> 7, d = c2 & 127;
            long o = ((long)((b * 8 + h) * 2048 + s)) * 128 + d;
            nv[o] = v;
            vb[((long)((b * 8 + h) * 128 + d)) * 2048 + s] = f2bf(v);  // [b][hkv][d][s]
          }
        }
      }
    }
  }
}

// ---------------- RoPE in-place on q and k (bf16, interleaved pairs) --------
__global__ __launch_bounds__(256) void rope_kernel(short* __restrict__ qb,
                                                   short* __restrict__ kb) {
  const long QV = 2097152;
  const long TV = 2621440;
  long i = (long)blockIdx.x * 256 + threadIdx.x;
  if (i >= TV) return;
  short* p;
  long e;
  if (i < QV) { e = i * 8; p = qb + e; }
  else        { e = (i - QV) * 8; p = kb + e; }
  int d0 = (int)(e & 127);
  int s  = (int)((e >> 7) & 2047);
  int jb = d0 >> 1;
  s16x8 v = *(const s16x8*)p;
  #pragma unroll
  for (int t = 0; t < 4; ++t) {
    float x1 = bf2f(v[2 * t]), x2 = bf2f(v[2 * t + 1]);
    int j = jb + t;
    float inv = __expf(-0.14391157f * (float)j);  // 10000^(-2j/128)
    float ang = (float)s * inv;
    float sn, cs;
    __sincosf(ang, &sn, &cs);
    v[2 * t]     = f2bf(x1 * cs - x2 * sn);
    v[2 * t + 1] = f2bf(x1 * sn + x2 * cs);
  }
  *(s16x8*)p = v;
}

// ---------------- Flash attention v5: LPT dispatch, swapped-QK --------------
__global__ __launch_bounds__(256) void flash_kernel(
    const short* __restrict__ qb, const short* __restrict__ kb,
    const short* __restrict__ vt, short* __restrict__ ao)
{
  const int bid = blockIdx.x;
  const int qt = 15 - (bid >> 6);   // true LPT: heaviest blocks dispatch first
  const int hb = bid & 63;
  const int h = hb & 31, b = hb >> 5;
  const int hkv = h >> 2;
  const int tid = threadIdx.x, w = tid >> 6, lane = tid & 63;
  const int l31 = lane & 31, hi = lane >> 5;
  const int hi16 = hi * 16;
  const int q0 = qt * 128 + w * 32;
  const int q_abs = q0 + l31;

  const short* Q  = qb + (long)(b * 32 + h) * 2048 * 128;
  const char*  Kg = (const char*)(kb + (long)(b * 8 + hkv) * 2048 * 128);
  const char*  Vg = (const char*)(vt + (long)(b * 8 + hkv) * 2048 * 128);  // [d][s]

  __shared__ short Ks[2][64 * 128];  // [kv][d], 16B chunks XOR-swizzled by kv&7
  __shared__ short Vs[2][128 * 64];  // [d][kv], 16B chunks XOR-swizzled by d&7

  int skX[4], svRow[4], svCol[4], Xo[4];
  #pragma unroll
  for (int i2 = 0; i2 < 4; ++i2) {
    int X = tid * 16 + i2 * 4096;
    Xo[i2] = X;
    skX[i2] = X ^ (((X >> 8) & 7) << 4);
    int sv = X ^ (((X >> 7) & 7) << 4);
    svRow[i2] = sv >> 7;
    svCol[i2] = sv & 127;
  }

  bf16x8 qf[8];
  #pragma unroll
  for (int c = 0; c < 8; ++c)
    qf[c] = *(const bf16x8*)&Q[(long)q_abs * 128 + c * 16 + hi * 8];

  f32x16 o[4];
  #pragma unroll
  for (int db = 0; db < 4; ++db)
    #pragma unroll
    for (int r = 0; r < 16; ++r) o[db][r] = 0.f;
  float m_ = -3e38f, l_ = 0.f;

  const float scale2 = 0.08838834764831845f * 1.4426950408889634f;
  const int nt = 2 * (qt + 1);
  const int ksw = (l31 & 7) << 4;

  #pragma unroll
  for (int i2 = 0; i2 < 4; ++i2) {
    gload16(Kg + skX[i2], (char*)Ks[0] + Xo[i2]);
    gload16(Vg + ((long)svRow[i2] * 4096 + svCol[i2]), (char*)Vs[0] + Xo[i2]);
  }

  for (int t = 0; t < nt; ++t) {
    const int kv0 = t * 64;
    const int cur = t & 1;
    __syncthreads();
    if (t + 1 < nt) {
      const long kvb = (long)(kv0 + 64);
      #pragma unroll
      for (int i2 = 0; i2 < 4; ++i2) {
        gload16(Kg + kvb * 256 + skX[i2], (char*)Ks[cur ^ 1] + Xo[i2]);
        gload16(Vg + ((long)svRow[i2] * 4096 + kvb * 2 + svCol[i2]),
                (char*)Vs[cur ^ 1] + Xo[i2]);
      }
    }
    if (kv0 > q0 + 31) continue;

    f32x16 s0, s1;
    #pragma unroll
    for (int r = 0; r < 16; ++r) { s0[r] = 0.f; s1[r] = 0.f; }
    const char* kbase = (const char*)Ks[cur] + l31 * 256;
    __builtin_amdgcn_s_setprio(1);
    #pragma unroll
    for (int c = 0; c < 8; ++c) {
      bf16x8 kf0 = *(const bf16x8*)(kbase + ((c * 32 + hi16) ^ ksw));
      bf16x8 kf1 = *(const bf16x8*)(kbase + 8192 + ((c * 32 + hi16) ^ ksw));
      s0 = __builtin_amdgcn_mfma_f32_32x32x16_bf16(kf0, qf[c], s0, 0, 0, 0);
      s1 = __builtin_amdgcn_mfma_f32_32x32x16_bf16(kf1, qf[c], s1, 0, 0, 0);
    }
    __builtin_amdgcn_s_setprio(0);

    const bool diag = (kv0 + 63 > q0);
    if (diag) {
      #pragma unroll
      for (int r = 0; r < 16; ++r) {
        int krow = (r & 3) + 8 * (r >> 2) + 4 * hi;
        if (kv0 + krow > q_abs)      s0[r] = -3e38f;
        if (kv0 + 32 + krow > q_abs) s1[r] = -3e38f;
      }
    }
    float mx = fmaxf(s0[0], s1[0]);
    #pragma unroll
    for (int r = 1; r < 16; ++r) mx = fmaxf(mx, fmaxf(s0[r], s1[r]));
    mx *= scale2;
    mx = fmaxf(mx, __shfl_xor(mx, 32));
    int need = mx > m_ + 11.5f;
    if (__any(need)) {
      float mn = fmaxf(m_, mx);
      float fac = exp2f(m_ - mn);
      m_ = mn;
      l_ *= fac;
      #pragma unroll
      for (int db = 0; db < 4; ++db)
        #pragma unroll
        for (int r = 0; r < 16; ++r) o[db][r] *= fac;
    }
    float rs = 0.f;
    #pragma unroll
    for (int r = 0; r < 16; ++r) {
      float p0 = exp2f(fmaf(s0[r], scale2, -m_));
      float p1 = exp2f(fmaf(s1[r], scale2, -m_));
      s0[r] = p0; s1[r] = p1;
      rs += p0 + p1;
    }
    rs += __shfl_xor(rs, 32);
    l_ += rs;

    const char* vbase = (const char*)Vs[cur] + l31 * 128;
    #pragma unroll
    for (int t2 = 0; t2 < 2; ++t2) {
      const f32x16 sp = t2 ? s1 : s0;
      unsigned wd[8];
      #pragma unroll
      for (int jj = 0; jj < 8; ++jj) wd[jj] = cvtpk(sp[2 * jj], sp[2 * jj + 1]);
      unsigned u0 = hi ? wd[0] : wd[2];
      unsigned u1 = hi ? wd[1] : wd[3];
      unsigned u2 = hi ? wd[4] : wd[6];
      unsigned u3 = hi ? wd[5] : wd[7];
      unsigned x0 = (unsigned)__shfl_xor((int)u0, 32);
      unsigned x1 = (unsigned)__shfl_xor((int)u1, 32);
      unsigned x2 = (unsigned)__shfl_xor((int)u2, 32);
      unsigned x3 = (unsigned)__shfl_xor((int)u3, 32);
      BW f0, f1;
      f0.u[0] = hi ? x0 : wd[0];
      f0.u[1] = hi ? x1 : wd[1];
      f0.u[2] = hi ? wd[2] : x0;
      f0.u[3] = hi ? wd[3] : x1;
      f1.u[0] = hi ? x2 : wd[4];
      f1.u[1] = hi ? x3 : wd[5];
      f1.u[2] = hi ? wd[6] : x2;
      f1.u[3] = hi ? wd[7] : x3;
      __builtin_amdgcn_s_setprio(1);
      #pragma unroll
      for (int cc = 0; cc < 2; ++cc) {
        const BW& fr = cc ? f1 : f0;
        #pragma unroll
        for (int db = 0; db < 4; ++db) {
          bf16x8 vf = *(const bf16x8*)(vbase + db * 4096 +
                                       ((t2 * 64 + cc * 32 + hi16) ^ ksw));
          o[db] = __builtin_amdgcn_mfma_f32_32x32x16_bf16(vf, fr.v, o[db], 0, 0, 0);
        }
      }
      __builtin_amdgcn_s_setprio(0);
    }
  }

  float invl = 1.0f / l_;
  const long aorow = ((long)(b * 2048 + q_abs)) * 4096 + h * 128 + hi * 4;
  #pragma unroll
  for (int db = 0; db < 4; ++db)
    #pragma unroll
    for (int r = 0; r < 16; ++r) {
      int doff = db * 32 + (r & 3) + 8 * (r >> 2);
      ao[aorow + doff] = f2bf(o[db][r] * invl);
    }
}

// ---------------- launcher --------------------------------------------------
extern "C" void kernel_launch(void* const* d_in, const int* in_sizes, int n_in,
                              void* d_out, int out_size, void* d_ws, size_t ws_size,
                              hipStream_t stream) {
  const float* x  = (const float*)d_in[0];
  const float* wq = (const float*)d_in[1];
  const float* wk = (const float*)d_in[2];
  const float* wv = (const float*)d_in[3];
  const float* wo = (const float*)d_in[4];
  float* out = (float*)d_out;

  char* ws = (char*)d_ws;
  short* xb    = (short*)(ws);               // x bf16; later reused as attn_out
  short* wqkvb = (short*)(ws + 33554432);    // wq|wk|wv bf16 (6144x4096)
  short* wob   = (short*)(ws + 83886080);
  short* qb    = (short*)(ws + 117440512);   // (B,H,S,D)
  short* kb    = (short*)(ws + 150994944);   // (B,Hkv,S,D)
  short* vb    = (short*)(ws + 159383552);   // (B,Hkv,D,S)  TRANSPOSED
  short* ao    = xb;

  float* nk = out + 16777216;  // new_k fp32 (B,Hkv,S,D)
  float* nv = out + 20971520;  // new_v fp32

  cast_all<<<28672, 256, 0, stream>>>(x, wq, wk, wv, wo, xb, wqkvb, wob);

  gemm256<1><<<384, 512, 0, stream>>>(xb, wqkvb, nullptr, qb, kb, vb, nk, nv);
  rope_kernel<<<10240, 256, 0, stream>>>(qb, kb);
  flash_kernel<<<1024, 256, 0, stream>>>(qb, kb, vb, ao);
  gemm256<0><<<256, 512, 0, stream>>>(ao, wob, out, nullptr, nullptr, nullptr,
                                      nullptr, nullptr);
}

// Round 8
// 581.409 us; speedup vs baseline: 2.1557x; 1.0310x over previous
//
#include <hip/hip_runtime.h>
#include <hip/hip_bf16.h>

typedef __attribute__((ext_vector_type(8)))  short   s16x8;
typedef __attribute__((ext_vector_type(8)))  __bf16  bf16x8;
typedef __attribute__((ext_vector_type(4)))  float   f32x4;
typedef __attribute__((ext_vector_type(16))) float   f32x16;

#define DEV static __device__ __forceinline__

DEV short f2bf(float f) {
  unsigned u = __builtin_bit_cast(unsigned, f);
  u = (u + 0x7fff + ((u >> 16) & 1)) >> 16;
  return (short)u;
}
DEV float bf2f(short s) {
  unsigned u = ((unsigned)(unsigned short)s) << 16;
  return __builtin_bit_cast(float, u);
}

DEV void gload16(const void* g, void* l) {
  __builtin_amdgcn_global_load_lds(
      (const __attribute__((address_space(1))) unsigned int*)g,
      (__attribute__((address_space(3))) unsigned int*)l, 16, 0, 0);
}

DEV unsigned cvtpk(float lo, float hi) {
  unsigned r;
  asm("v_cvt_pk_bf16_f32 %0, %1, %2" : "=v"(r) : "v"(lo), "v"(hi));
  return r;
}

typedef union { unsigned u[4]; bf16x8 v; } BW;

// ---------------- fused cast fp32 -> bf16 for all 5 inputs ------------------
__global__ __launch_bounds__(256) void cast_all(
    const float* __restrict__ x,  const float* __restrict__ wq,
    const float* __restrict__ wk, const float* __restrict__ wv,
    const float* __restrict__ wo,
    short* __restrict__ xb, short* __restrict__ wqkvb, short* __restrict__ wob) {
  long i = (long)blockIdx.x * 256 + threadIdx.x;  // vector index
  const float* src;
  short* dst;
  long off;
  if (i < 2097152)       { src = x;  dst = xb;               off = i; }
  else if (i < 4194304)  { src = wq; dst = wqkvb;            off = i - 2097152; }
  else if (i < 4718592)  { src = wk; dst = wqkvb + 16777216; off = i - 4194304; }
  else if (i < 5242880)  { src = wv; dst = wqkvb + 20971520; off = i - 4718592; }
  else                   { src = wo; dst = wob;              off = i - 5242880; }
  long e = off * 8;
  float4 a = *(const float4*)(src + e);
  float4 b = *(const float4*)(src + e + 4);
  s16x8 o;
  o[0] = f2bf(a.x); o[1] = f2bf(a.y); o[2] = f2bf(a.z); o[3] = f2bf(a.w);
  o[4] = f2bf(b.x); o[5] = f2bf(b.y); o[6] = f2bf(b.z); o[7] = f2bf(b.w);
  *(s16x8*)(dst + e) = o;
}

// ---------------- GEMM 256x128 tile, BK=64, 3-buffer rotating pipeline ------
// C[M][N] = A[M][K] @ W[N][K]^T, bf16 in, fp32 acc. K=4096 fixed (64 tiles).
// 8 waves 4x2, wave tile 64x64, acc[4][4]. LDS 3 x (A 32K + B 16K) = 144KB.
// Tile t reads buf[t%3]. Per tile: ONE vmcnt(6) (tile t+1 landed, tile t+2
// stays in flight) + ONE barrier, then STAGE(t+3) into the just-freed buffer.
// 2-body staging lookahead -> HBM latency fully hidden. XOR swizzle (row&7)<<4
// with pre-swizzled global source (rule #21). Grids: MODE1 768=3x256,
// MODE0 512=2x256 -> zero dispatch tail. XCD supertile mapping.
template<int MODE>
__global__ __launch_bounds__(512, 2) void gemm256(
    const short* __restrict__ A, const short* __restrict__ W,
    float* __restrict__ Cout,
    short* __restrict__ qb, short* __restrict__ kb, short* __restrict__ vb,
    float* __restrict__ nk, float* __restrict__ nv)
{
  __shared__ short lds[3][24576];  // 3 x 48KB: A at +0 (32KB), B at +32768

  const int tid = threadIdx.x;
  const int lane = tid & 63;
  const int w = tid >> 6;
  const int wm = w >> 1, wn = w & 1;          // 4 x 2 waves
  const int l15 = lane & 15, lg = lane >> 4;
  const int swz = (l15 & 7) << 4;

  // XCD supertile: c = bid&7 owns rect (c>>2)*8 tm-rows x (c&3)*RTN tn-cols
  const int RTN = MODE ? 12 : 8;
  int c = blockIdx.x & 7, j = blockIdx.x >> 3;
  const int tm = (c >> 2) * 8 + (j & 7);
  const int tn = (c & 3) * RTN + (j >> 3);

  const char* Ac = (const char*)A;
  const char* Wc = (const char*)W;

  // staging: dest X linear, source col pre-swizzled (rule #21)
  int aXo[4], bXo[2];
  long aSrc[4], bSrc[2];
  #pragma unroll
  for (int l4 = 0; l4 < 4; ++l4) {
    int X = tid * 16 + l4 * 8192;           // 0..32767 (A region)
    int row = X >> 7;                        // 0..255
    int colS = (X & 127) ^ (((X >> 7) & 7) << 4);
    aXo[l4] = X;
    aSrc[l4] = (long)(tm * 256 + row) * 8192 + colS;
  }
  #pragma unroll
  for (int l4 = 0; l4 < 2; ++l4) {
    int X = tid * 16 + l4 * 8192;           // 0..16383 (B region)
    int row = X >> 7;                        // 0..127
    int colS = (X & 127) ^ (((X >> 7) & 7) << 4);
    bXo[l4] = X;
    bSrc[l4] = (long)(tn * 128 + row) * 8192 + colS;
  }

#define STAGE(TT, BI)                                                        \
  {                                                                          \
    const long kof_ = (long)(TT) * 128;                                      \
    _Pragma("unroll")                                                        \
    for (int l4 = 0; l4 < 4; ++l4)                                           \
      gload16(Ac + aSrc[l4] + kof_, (char*)&lds[BI][0] + aXo[l4]);           \
    _Pragma("unroll")                                                        \
    for (int l4 = 0; l4 < 2; ++l4)                                           \
      gload16(Wc + bSrc[l4] + kof_, (char*)&lds[BI][0] + 32768 + bXo[l4]);   \
  }

  f32x4 zero = {0.f, 0.f, 0.f, 0.f};
  f32x4 acc[4][4];
  #pragma unroll
  for (int i = 0; i < 4; ++i)
    #pragma unroll
    for (int jj = 0; jj < 4; ++jj) acc[i][jj] = zero;

  const int aro = (wm * 64 + l15) * 128;           // A byte row base
  const int bro = 32768 + (wn * 64 + l15) * 128;   // B byte row base
  const int cs0 = (lg << 4) ^ swz;                 // khalf 0
  const int cs1 = (64 | (lg << 4)) ^ swz;          // khalf 1

#define MF(a0, a1, MR)                                                       \
  __builtin_amdgcn_s_setprio(1);                                             \
  _Pragma("unroll")                                                          \
  for (int nr = 0; nr < 4; ++nr) {                                           \
    acc[MR][nr] = __builtin_amdgcn_mfma_f32_16x16x32_bf16(                   \
        a0, bfr[nr][0], acc[MR][nr], 0, 0, 0);                               \
    acc[MR][nr] = __builtin_amdgcn_mfma_f32_16x16x32_bf16(                   \
        a1, bfr[nr][1], acc[MR][nr], 0, 0, 0);                               \
  }                                                                          \
  __builtin_amdgcn_s_setprio(0);

// One K-tile: ds-pipelined 4 phases (ping-pong A), then vmcnt+barrier+stage.
#define TILE(T, BI)                                                          \
  {                                                                          \
    const char* L = (const char*)&lds[BI][0];                                \
    bf16x8 bfr[4][2];                                                        \
    _Pragma("unroll")                                                        \
    for (int nr = 0; nr < 4; ++nr) {                                         \
      bfr[nr][0] = *(const bf16x8*)(L + bro + nr * 2048 + cs0);              \
      bfr[nr][1] = *(const bf16x8*)(L + bro + nr * 2048 + cs1);              \
    }                                                                        \
    bf16x8 g0, g1, h0, h1;                                                   \
    g0 = *(const bf16x8*)(L + aro + 0 * 2048 + cs0);                         \
    g1 = *(const bf16x8*)(L + aro + 0 * 2048 + cs1);                         \
    h0 = *(const bf16x8*)(L + aro + 1 * 2048 + cs0);                         \
    h1 = *(const bf16x8*)(L + aro + 1 * 2048 + cs1);                         \
    asm volatile("s_waitcnt lgkmcnt(2)" ::: "memory");                       \
    __builtin_amdgcn_sched_barrier(0);                                       \
    MF(g0, g1, 0)                                                            \
    g0 = *(const bf16x8*)(L + aro + 2 * 2048 + cs0);                         \
    g1 = *(const bf16x8*)(L + aro + 2 * 2048 + cs1);                         \
    asm volatile("s_waitcnt lgkmcnt(2)" ::: "memory");                       \
    __builtin_amdgcn_sched_barrier(0);                                       \
    MF(h0, h1, 1)                                                            \
    h0 = *(const bf16x8*)(L + aro + 3 * 2048 + cs0);                         \
    h1 = *(const bf16x8*)(L + aro + 3 * 2048 + cs1);                         \
    asm volatile("s_waitcnt lgkmcnt(2)" ::: "memory");                       \
    __builtin_amdgcn_sched_barrier(0);                                       \
    MF(g0, g1, 2)                                                            \
    asm volatile("s_waitcnt lgkmcnt(0)" ::: "memory");                       \
    __builtin_amdgcn_sched_barrier(0);                                       \
    MF(h0, h1, 3)                                                            \
    if ((T) < 62) {                                                          \
      asm volatile("s_waitcnt vmcnt(6)" ::: "memory");                       \
    } else if ((T) == 62) {                                                  \
      asm volatile("s_waitcnt vmcnt(0)" ::: "memory");                       \
    }                                                                        \
    if ((T) < 63) __builtin_amdgcn_s_barrier();                              \
    if ((T) < 61) { STAGE((T) + 3, BI) }                                     \
  }

  // prologue: stage tiles 0,1,2; ensure tile 0 landed block-wide
  STAGE(0, 0)
  STAGE(1, 1)
  STAGE(2, 2)
  asm volatile("s_waitcnt vmcnt(12)" ::: "memory");
  __builtin_amdgcn_s_barrier();

  #pragma clang loop unroll(disable)
  for (int t3 = 0; t3 < 63; t3 += 3) {
    TILE(t3 + 0, 0)
    TILE(t3 + 1, 1)
    TILE(t3 + 2, 2)
  }
  TILE(63, 0)

#undef STAGE
#undef TILE
#undef MF

  // epilogue
  #pragma unroll
  for (int mr = 0; mr < 4; ++mr) {
    int mbase = tm * 256 + wm * 64 + mr * 16 + lg * 4;
    #pragma unroll
    for (int nr = 0; nr < 4; ++nr) {
      int col = tn * 128 + wn * 64 + nr * 16 + l15;
      #pragma unroll
      for (int r = 0; r < 4; ++r) {
        int m = mbase + r;
        float v = acc[mr][nr][r];
        if (MODE == 0) {
          Cout[(long)m * 4096 + col] = v;
        } else {
          int b = m >> 11, s = m & 2047;
          if (col < 4096) {
            int h = col >> 7, d = col & 127;
            qb[((long)((b * 32 + h) * 2048 + s)) * 128 + d] = f2bf(v);
          } else if (col < 5120) {
            int c2 = col - 4096;
            int h = c2 >> 7, d = c2 & 127;
            long o = ((long)((b * 8 + h) * 2048 + s)) * 128 + d;
            kb[o] = f2bf(v);
            nk[o] = v;
          } else {
            int c2 = col - 5120;
            int h = c2 >> 7, d = c2 & 127;
            long o = ((long)((b * 8 + h) * 2048 + s)) * 128 + d;
            nv[o] = v;
            vb[((long)((b * 8 + h) * 128 + d)) * 2048 + s] = f2bf(v);  // [b][hkv][d][s]
          }
        }
      }
    }
  }
}

// ---------------- RoPE in-place on q and k (bf16, interleaved pairs) --------
__global__ __launch_bounds__(256) void rope_kernel(short* __restrict__ qb,
                                                   short* __restrict__ kb) {
  const long QV = 2097152;
  const long TV = 2621440;
  long i = (long)blockIdx.x * 256 + threadIdx.x;
  if (i >= TV) return;
  short* p;
  long e;
  if (i < QV) { e = i * 8; p = qb + e; }
  else        { e = (i - QV) * 8; p = kb + e; }
  int d0 = (int)(e & 127);
  int s  = (int)((e >> 7) & 2047);
  int jb = d0 >> 1;
  s16x8 v = *(const s16x8*)p;
  #pragma unroll
  for (int t = 0; t < 4; ++t) {
    float x1 = bf2f(v[2 * t]), x2 = bf2f(v[2 * t + 1]);
    int j = jb + t;
    float inv = __expf(-0.14391157f * (float)j);  // 10000^(-2j/128)
    float ang = (float)s * inv;
    float sn, cs;
    __sincosf(ang, &sn, &cs);
    v[2 * t]     = f2bf(x1 * cs - x2 * sn);
    v[2 * t + 1] = f2bf(x1 * sn + x2 * cs);
  }
  *(s16x8*)p = v;
}

// ---------------- Flash attention v5: LPT dispatch, swapped-QK --------------
__global__ __launch_bounds__(256) void flash_kernel(
    const short* __restrict__ qb, const short* __restrict__ kb,
    const short* __restrict__ vt, short* __restrict__ ao)
{
  const int bid = blockIdx.x;
  const int qt = 15 - (bid >> 6);   // true LPT: heaviest blocks dispatch first
  const int hb = bid & 63;
  const int h = hb & 31, b = hb >> 5;
  const int hkv = h >> 2;
  const int tid = threadIdx.x, w = tid >> 6, lane = tid & 63;
  const int l31 = lane & 31, hi = lane >> 5;
  const int hi16 = hi * 16;
  const int q0 = qt * 128 + w * 32;
  const int q_abs = q0 + l31;

  const short* Q  = qb + (long)(b * 32 + h) * 2048 * 128;
  const char*  Kg = (const char*)(kb + (long)(b * 8 + hkv) * 2048 * 128);
  const char*  Vg = (const char*)(vt + (long)(b * 8 + hkv) * 2048 * 128);  // [d][s]

  __shared__ short Ks[2][64 * 128];  // [kv][d], 16B chunks XOR-swizzled by kv&7
  __shared__ short Vs[2][128 * 64];  // [d][kv], 16B chunks XOR-swizzled by d&7

  int skX[4], svRow[4], svCol[4], Xo[4];
  #pragma unroll
  for (int i2 = 0; i2 < 4; ++i2) {
    int X = tid * 16 + i2 * 4096;
    Xo[i2] = X;
    skX[i2] = X ^ (((X >> 8) & 7) << 4);
    int sv = X ^ (((X >> 7) & 7) << 4);
    svRow[i2] = sv >> 7;
    svCol[i2] = sv & 127;
  }

  bf16x8 qf[8];
  #pragma unroll
  for (int c = 0; c < 8; ++c)
    qf[c] = *(const bf16x8*)&Q[(long)q_abs * 128 + c * 16 + hi * 8];

  f32x16 o[4];
  #pragma unroll
  for (int db = 0; db < 4; ++db)
    #pragma unroll
    for (int r = 0; r < 16; ++r) o[db][r] = 0.f;
  float m_ = -3e38f, l_ = 0.f;

  const float scale2 = 0.08838834764831845f * 1.4426950408889634f;
  const int nt = 2 * (qt + 1);
  const int ksw = (l31 & 7) << 4;

  #pragma unroll
  for (int i2 = 0; i2 < 4; ++i2) {
    gload16(Kg + skX[i2], (char*)Ks[0] + Xo[i2]);
    gload16(Vg + ((long)svRow[i2] * 4096 + svCol[i2]), (char*)Vs[0] + Xo[i2]);
  }

  for (int t = 0; t < nt; ++t) {
    const int kv0 = t * 64;
    const int cur = t & 1;
    __syncthreads();
    if (t + 1 < nt) {
      const long kvb = (long)(kv0 + 64);
      #pragma unroll
      for (int i2 = 0; i2 < 4; ++i2) {
        gload16(Kg + kvb * 256 + skX[i2], (char*)Ks[cur ^ 1] + Xo[i2]);
        gload16(Vg + ((long)svRow[i2] * 4096 + kvb * 2 + svCol[i2]),
                (char*)Vs[cur ^ 1] + Xo[i2]);
      }
    }
    if (kv0 > q0 + 31) continue;

    f32x16 s0, s1;
    #pragma unroll
    for (int r = 0; r < 16; ++r) { s0[r] = 0.f; s1[r] = 0.f; }
    const char* kbase = (const char*)Ks[cur] + l31 * 256;
    __builtin_amdgcn_s_setprio(1);
    #pragma unroll
    for (int c = 0; c < 8; ++c) {
      bf16x8 kf0 = *(const bf16x8*)(kbase + ((c * 32 + hi16) ^ ksw));
      bf16x8 kf1 = *(const bf16x8*)(kbase + 8192 + ((c * 32 + hi16) ^ ksw));
      s0 = __builtin_amdgcn_mfma_f32_32x32x16_bf16(kf0, qf[c], s0, 0, 0, 0);
      s1 = __builtin_amdgcn_mfma_f32_32x32x16_bf16(kf1, qf[c], s1, 0, 0, 0);
    }
    __builtin_amdgcn_s_setprio(0);

    const bool diag = (kv0 + 63 > q0);
    if (diag) {
      #pragma unroll
      for (int r = 0; r < 16; ++r) {
        int krow = (r & 3) + 8 * (r >> 2) + 4 * hi;
        if (kv0 + krow > q_abs)      s0[r] = -3e38f;
        if (kv0 + 32 + krow > q_abs) s1[r] = -3e38f;
      }
    }
    float mx = fmaxf(s0[0], s1[0]);
    #pragma unroll
    for (int r = 1; r < 16; ++r) mx = fmaxf(mx, fmaxf(s0[r], s1[r]));
    mx *= scale2;
    mx = fmaxf(mx, __shfl_xor(mx, 32));
    int need = mx > m_ + 11.5f;
    if (__any(need)) {
      float mn = fmaxf(m_, mx);
      float fac = exp2f(m_ - mn);
      m_ = mn;
      l_ *= fac;
      #pragma unroll
      for (int db = 0; db < 4; ++db)
        #pragma unroll
        for (int r = 0; r < 16; ++r) o[db][r] *= fac;
    }
    float rs = 0.f;
    #pragma unroll
    for (int r = 0; r < 16; ++r) {
      float p0 = exp2f(fmaf(s0[r], scale2, -m_));
      float p1 = exp2f(fmaf(s1[r], scale2, -m_));
      s0[r] = p0; s1[r] = p1;
      rs += p0 + p1;
    }
    rs += __shfl_xor(rs, 32);
    l_ += rs;

    const char* vbase = (const char*)Vs[cur] + l31 * 128;
    #pragma unroll
    for (int t2 = 0; t2 < 2; ++t2) {
      const f32x16 sp = t2 ? s1 : s0;
      unsigned wd[8];
      #pragma unroll
      for (int jj = 0; jj < 8; ++jj) wd[jj] = cvtpk(sp[2 * jj], sp[2 * jj + 1]);
      unsigned u0 = hi ? wd[0] : wd[2];
      unsigned u1 = hi ? wd[1] : wd[3];
      unsigned u2 = hi ? wd[4] : wd[6];
      unsigned u3 = hi ? wd[5] : wd[7];
      unsigned x0 = (unsigned)__shfl_xor((int)u0, 32);
      unsigned x1 = (unsigned)__shfl_xor((int)u1, 32);
      unsigned x2 = (unsigned)__shfl_xor((int)u2, 32);
      unsigned x3 = (unsigned)__shfl_xor((int)u3, 32);
      BW f0, f1;
      f0.u[0] = hi ? x0 : wd[0];
      f0.u[1] = hi ? x1 : wd[1];
      f0.u[2] = hi ? wd[2] : x0;
      f0.u[3] = hi ? wd[3] : x1;
      f1.u[0] = hi ? x2 : wd[4];
      f1.u[1] = hi ? x3 : wd[5];
      f1.u[2] = hi ? wd[6] : x2;
      f1.u[3] = hi ? wd[7] : x3;
      __builtin_amdgcn_s_setprio(1);
      #pragma unroll
      for (int cc = 0; cc < 2; ++cc) {
        const BW& fr = cc ? f1 : f0;
        #pragma unroll
        for (int db = 0; db < 4; ++db) {
          bf16x8 vf = *(const bf16x8*)(vbase + db * 4096 +
                                       ((t2 * 64 + cc * 32 + hi16) ^ ksw));
          o[db] = __builtin_amdgcn_mfma_f32_32x32x16_bf16(vf, fr.v, o[db], 0, 0, 0);
        }
      }
      __builtin_amdgcn_s_setprio(0);
    }
  }

  float invl = 1.0f / l_;
  const long aorow = ((long)(b * 2048 + q_abs)) * 4096 + h * 128 + hi * 4;
  #pragma unroll
  for (int db = 0; db < 4; ++db)
    #pragma unroll
    for (int r = 0; r < 16; ++r) {
      int doff = db * 32 + (r & 3) + 8 * (r >> 2);
      ao[aorow + doff] = f2bf(o[db][r] * invl);
    }
}

// ---------------- launcher --------------------------------------------------
extern "C" void kernel_launch(void* const* d_in, const int* in_sizes, int n_in,
                              void* d_out, int out_size, void* d_ws, size_t ws_size,
                              hipStream_t stream) {
  const float* x  = (const float*)d_in[0];
  const float* wq = (const float*)d_in[1];
  const float* wk = (const float*)d_in[2];
  const float* wv = (const float*)d_in[3];
  const float* wo = (const float*)d_in[4];
  float* out = (float*)d_out;

  char* ws = (char*)d_ws;
  short* xb    = (short*)(ws);               // x bf16; later reused as attn_out
  short* wqkvb = (short*)(ws + 33554432);    // wq|wk|wv bf16 (6144x4096)
  short* wob   = (short*)(ws + 83886080);
  short* qb    = (short*)(ws + 117440512);   // (B,H,S,D)
  short* kb    = (short*)(ws + 150994944);   // (B,Hkv,S,D)
  short* vb    = (short*)(ws + 159383552);   // (B,Hkv,D,S)  TRANSPOSED
  short* ao    = xb;

  float* nk = out + 16777216;  // new_k fp32 (B,Hkv,S,D)
  float* nv = out + 20971520;  // new_v fp32

  cast_all<<<28672, 256, 0, stream>>>(x, wq, wk, wv, wo, xb, wqkvb, wob);

  gemm256<1><<<768, 512, 0, stream>>>(xb, wqkvb, nullptr, qb, kb, vb, nk, nv);
  rope_kernel<<<10240, 256, 0, stream>>>(qb, kb);
  flash_kernel<<<1024, 256, 0, stream>>>(qb, kb, vb, ao);
  gemm256<0><<<512, 512, 0, stream>>>(ao, wob, out, nullptr, nullptr, nullptr,
                                      nullptr, nullptr);
}